// Round 13
// baseline (257.346 us; speedup 1.0000x reference)
//
#include <hip/hip_runtime.h>
#include <hip/hip_bf16.h>

// GATv2 2-layer GNN. Round 13: true 8-phase-style GEMM schedule (m201 port):
// BK=32, 4 phases/K-tile {ds_read 2 A-frags | issue 2 gload | barrier |
// lgkmcnt(0) | setprio MFMA x16 | barrier}, 3 LDS buffers, 2-deep prefetch,
// counted vmcnt(6) once per K-tile. bf16 activations throughout (round 12).
// N=32768 (64 graphs x 512), F=512, E=262144 (+N self loops), H=4, C1=128, C2=64.

typedef __bf16 bf16_t;
typedef bf16_t bf16x8 __attribute__((ext_vector_type(8)));
typedef float f32x4 __attribute__((ext_vector_type(4)));
typedef unsigned short ushort8 __attribute__((ext_vector_type(8)));
typedef unsigned short ushort4v __attribute__((ext_vector_type(4)));

__device__ __forceinline__ unsigned short f2bf_rn(float f) {
    unsigned u = __float_as_uint(f);
    unsigned r = (u + 0x7FFFu + ((u >> 16) & 1u)) >> 16;
    return (unsigned short)r;
}
__device__ __forceinline__ float bf2f(unsigned short h) {
    return __uint_as_float((unsigned)h << 16);
}

// ---------------- CSR build ----------------

__global__ void hist_kernel(const int* __restrict__ ei, int E, int N,
                            int* __restrict__ deg) {
    int total = E + N;
    for (int e = blockIdx.x * blockDim.x + threadIdx.x; e < total;
         e += gridDim.x * blockDim.x) {
        int dst = (e < E) ? ei[E + e] : (e - E);
        atomicAdd(&deg[dst], 1);
    }
}

__global__ __launch_bounds__(512) void scan_pg(const int* __restrict__ deg,
                                               int* __restrict__ off,
                                               int NPG, int EPG) {
    __shared__ int buf[512];
    int g = blockIdx.x, tid = threadIdx.x;
    int base = g * NPG;
    buf[tid] = deg[base + tid];
    __syncthreads();
    #pragma unroll
    for (int ofs = 1; ofs < 512; ofs <<= 1) {
        int t = (tid >= ofs) ? buf[tid - ofs] : 0;
        __syncthreads();
        buf[tid] += t;
        __syncthreads();
    }
    off[base + tid + 1] = g * EPG + buf[tid];
    if (tid == 0) off[base] = g * EPG;
}

__global__ void scatter_kernel(const int* __restrict__ ei, int E, int N,
                               const int* __restrict__ off, int* __restrict__ cnt,
                               int* __restrict__ csrc) {
    int total = E + N;
    for (int e = blockIdx.x * blockDim.x + threadIdx.x; e < total;
         e += gridDim.x * blockDim.x) {
        int src, dst;
        if (e < E) { src = ei[e]; dst = ei[E + e]; }
        else       { src = e - E; dst = e - E; }
        int pos = off[dst] + atomicAdd(&cnt[dst], 1);
        csrc[pos] = src;
    }
}

// ---------------- fp32 -> bf16 cast (hi only) ----------------

__global__ __launch_bounds__(256) void cast_hi_kernel(
        const float* __restrict__ X, unsigned short* __restrict__ hi, int n4) {
    for (int i = blockIdx.x * blockDim.x + threadIdx.x; i < n4;
         i += gridDim.x * blockDim.x) {
        float4 v = ((const float4*)X)[i];
        ushort4 h;
        h.x = f2bf_rn(v.x); h.y = f2bf_rn(v.y);
        h.z = f2bf_rn(v.z); h.w = f2bf_rn(v.w);
        ((ushort4*)hi)[i] = h;
    }
}

// W [K][Nc] fp32 -> Wt hi/lo [Nc][K] bf16 (transpose + decompose)
__global__ __launch_bounds__(256) void tdecomp_kernel(
        const float* __restrict__ W, unsigned short* __restrict__ th,
        unsigned short* __restrict__ tl, int K, int Nc) {
    __shared__ float t[32][33];
    int bx = blockIdx.x, by = blockIdx.y;
    int lx = threadIdx.x & 31, ly = threadIdx.x >> 5;
    #pragma unroll
    for (int r = ly; r < 32; r += 8)
        t[r][lx] = W[(size_t)(by * 32 + r) * Nc + bx * 32 + lx];
    __syncthreads();
    #pragma unroll
    for (int r = ly; r < 32; r += 8) {
        float v = t[lx][r];
        unsigned short hb = f2bf_rn(v);
        float hf = __uint_as_float((unsigned)hb << 16);
        unsigned short lb = f2bf_rn(v - hf);
        size_t o = (size_t)(bx * 32 + r) * K + by * 32 + lx;
        th[o] = hb; tl[o] = lb;
    }
}

// ----- 256x256 GEMM, 8 waves, 2-product, phase-interleaved pipeline --------
// C(bf16) = Ah@(Bh+Bl)^T + bias. Bt [Nc][K]; BK=32; 4 phases per K-tile.
// 3 LDS buffers (A|Bh|Bl, 16KB each = 48KB/buf); 2-deep prefetch; vmcnt(6)
// once per K-tile (phase 3). Conflict-free slot swizzle (row>>1)&3.

#define LGKM0 do { asm volatile("s_waitcnt lgkmcnt(0)" ::: "memory"); \
                   __builtin_amdgcn_sched_barrier(0); } while (0)
#define VM6   do { asm volatile("s_waitcnt vmcnt(6)" ::: "memory"); \
                   __builtin_amdgcn_sched_barrier(0); } while (0)
#define VM0   do { asm volatile("s_waitcnt vmcnt(0)" ::: "memory"); \
                   __builtin_amdgcn_sched_barrier(0); } while (0)

__global__ __launch_bounds__(512) void gemm256p8(
        const unsigned short* __restrict__ Ah,
        const unsigned short* __restrict__ Bh, const unsigned short* __restrict__ Bl,
        const float* __restrict__ bias, unsigned short* __restrict__ C,
        int M, int K, int Nc) {
    constexpr int NQ  = 6;
    constexpr int BUF = 49152;
    __shared__ __align__(16) char smem[3 * BUF];

    int tid  = threadIdx.x;
    int wave = tid >> 6, lane = tid & 63;
    int wr = wave >> 2, wc = wave & 3;          // 2 x 4 wave grid, 128x64/wave

    int bx = blockIdx.x, by = blockIdx.y;
    if ((gridDim.y & 7) == 0) {                 // XCD swizzle: A-panel -> one XCD
        int d = blockIdx.y * gridDim.x + blockIdx.x;
        int x = d & 7, i = d >> 3;
        by = (i / gridDim.x) * 8 + x;
        bx = i % gridDim.x;
    }
    int m0 = by * 256, n0 = bx * 256;

    const unsigned short* gsrc[NQ];
    int loff[NQ];
    #pragma unroll
    for (int q = 0; q < NQ; ++q) {
        int o    = q * 8192 + tid * 16;
        int tile = o >> 14;
        int ot   = o & 16383;
        int row  = ot >> 6;
        int slot = (ot >> 4) & 3;
        int sl   = slot ^ ((row >> 1) & 3);     // conflict-free involution
        const unsigned short* base =
            (tile == 0) ? (Ah + (size_t)(m0 + row) * K) :
            (tile == 1) ? (Bh + (size_t)(n0 + row) * K) :
                          (Bl + (size_t)(n0 + row) * K);
        gsrc[q] = base + sl * 8;
        loff[q] = q * 8192 + wave * 1024;
    }

    f32x4 acc[8][4];
    #pragma unroll
    for (int i = 0; i < 8; ++i)
        #pragma unroll
        for (int j = 0; j < 4; ++j) acc[i][j] = (f32x4){0.f, 0.f, 0.f, 0.f};

    int r = lane & 15, g = lane >> 4;
    int sw = (g ^ ((r >> 1) & 3)) * 16;

    // prologue: tile0 -> buf0, tile1 -> buf1; wait tile0 (6 in flight ok)
    #pragma unroll
    for (int q = 0; q < NQ; ++q) {
        __builtin_amdgcn_global_load_lds(
            (const __attribute__((address_space(1))) void*)(gsrc[q]),
            (__attribute__((address_space(3))) void*)(smem + loff[q]), 16, 0, 0);
        gsrc[q] += 32;
    }
    #pragma unroll
    for (int q = 0; q < NQ; ++q) {
        __builtin_amdgcn_global_load_lds(
            (const __attribute__((address_space(1))) void*)(gsrc[q]),
            (__attribute__((address_space(3))) void*)(smem + BUF + loff[q]), 16, 0, 0);
        gsrc[q] += 32;
    }
    VM6;
    __builtin_amdgcn_s_barrier();

    const int NT = K >> 5;
    int cur = 0, nx2 = 2;
    for (int t = 0; t < NT; ++t) {
        const char* sb = smem + cur * BUF;
        char* nb = smem + nx2 * BUF;
        bool pre = (t + 2 < NT);
        bf16x8 vbh[4], vbl[4];

        // ---------------- phase 0: B frags + A rows 0,1 ----------------
        #pragma unroll
        for (int j = 0; j < 4; ++j) {
            int offB = (wc * 64 + j * 16 + r) * 64 + sw;
            vbh[j] = *(const bf16x8*)(sb + 16384 + offB);
            vbl[j] = *(const bf16x8*)(sb + 32768 + offB);
        }
        {
            bf16x8 a0 = *(const bf16x8*)(sb + (wr * 128 + 0 * 16 + r) * 64 + sw);
            bf16x8 a1 = *(const bf16x8*)(sb + (wr * 128 + 1 * 16 + r) * 64 + sw);
            if (pre) {
                #pragma unroll
                for (int q = 0; q < 2; ++q) {
                    __builtin_amdgcn_global_load_lds(
                        (const __attribute__((address_space(1))) void*)(gsrc[q]),
                        (__attribute__((address_space(3))) void*)(nb + loff[q]), 16, 0, 0);
                    gsrc[q] += 32;
                }
            }
            __builtin_amdgcn_s_barrier();
            LGKM0;
            __builtin_amdgcn_s_setprio(1);
            #pragma unroll
            for (int j = 0; j < 4; ++j) {
                acc[0][j] = __builtin_amdgcn_mfma_f32_16x16x32_bf16(a0, vbh[j], acc[0][j], 0, 0, 0);
                acc[0][j] = __builtin_amdgcn_mfma_f32_16x16x32_bf16(a0, vbl[j], acc[0][j], 0, 0, 0);
                acc[1][j] = __builtin_amdgcn_mfma_f32_16x16x32_bf16(a1, vbh[j], acc[1][j], 0, 0, 0);
                acc[1][j] = __builtin_amdgcn_mfma_f32_16x16x32_bf16(a1, vbl[j], acc[1][j], 0, 0, 0);
            }
            __builtin_amdgcn_s_setprio(0);
            __builtin_amdgcn_s_barrier();
        }
        // ---------------- phase 1: A rows 2,3 ----------------
        {
            bf16x8 a0 = *(const bf16x8*)(sb + (wr * 128 + 2 * 16 + r) * 64 + sw);
            bf16x8 a1 = *(const bf16x8*)(sb + (wr * 128 + 3 * 16 + r) * 64 + sw);
            if (pre) {
                #pragma unroll
                for (int q = 2; q < 4; ++q) {
                    __builtin_amdgcn_global_load_lds(
                        (const __attribute__((address_space(1))) void*)(gsrc[q]),
                        (__attribute__((address_space(3))) void*)(nb + loff[q]), 16, 0, 0);
                    gsrc[q] += 32;
                }
            }
            __builtin_amdgcn_s_barrier();
            LGKM0;
            __builtin_amdgcn_s_setprio(1);
            #pragma unroll
            for (int j = 0; j < 4; ++j) {
                acc[2][j] = __builtin_amdgcn_mfma_f32_16x16x32_bf16(a0, vbh[j], acc[2][j], 0, 0, 0);
                acc[2][j] = __builtin_amdgcn_mfma_f32_16x16x32_bf16(a0, vbl[j], acc[2][j], 0, 0, 0);
                acc[3][j] = __builtin_amdgcn_mfma_f32_16x16x32_bf16(a1, vbh[j], acc[3][j], 0, 0, 0);
                acc[3][j] = __builtin_amdgcn_mfma_f32_16x16x32_bf16(a1, vbl[j], acc[3][j], 0, 0, 0);
            }
            __builtin_amdgcn_s_setprio(0);
            __builtin_amdgcn_s_barrier();
        }
        // ---------------- phase 2: A rows 4,5 ----------------
        {
            bf16x8 a0 = *(const bf16x8*)(sb + (wr * 128 + 4 * 16 + r) * 64 + sw);
            bf16x8 a1 = *(const bf16x8*)(sb + (wr * 128 + 5 * 16 + r) * 64 + sw);
            if (pre) {
                #pragma unroll
                for (int q = 4; q < 6; ++q) {
                    __builtin_amdgcn_global_load_lds(
                        (const __attribute__((address_space(1))) void*)(gsrc[q]),
                        (__attribute__((address_space(3))) void*)(nb + loff[q]), 16, 0, 0);
                    gsrc[q] += 32;
                }
            }
            __builtin_amdgcn_s_barrier();
            LGKM0;
            __builtin_amdgcn_s_setprio(1);
            #pragma unroll
            for (int j = 0; j < 4; ++j) {
                acc[4][j] = __builtin_amdgcn_mfma_f32_16x16x32_bf16(a0, vbh[j], acc[4][j], 0, 0, 0);
                acc[4][j] = __builtin_amdgcn_mfma_f32_16x16x32_bf16(a0, vbl[j], acc[4][j], 0, 0, 0);
                acc[5][j] = __builtin_amdgcn_mfma_f32_16x16x32_bf16(a1, vbh[j], acc[5][j], 0, 0, 0);
                acc[5][j] = __builtin_amdgcn_mfma_f32_16x16x32_bf16(a1, vbl[j], acc[5][j], 0, 0, 0);
            }
            __builtin_amdgcn_s_setprio(0);
            __builtin_amdgcn_s_barrier();
        }
        // ---------------- phase 3: A rows 6,7 + counted vmcnt ----------------
        {
            bf16x8 a0 = *(const bf16x8*)(sb + (wr * 128 + 6 * 16 + r) * 64 + sw);
            bf16x8 a1 = *(const bf16x8*)(sb + (wr * 128 + 7 * 16 + r) * 64 + sw);
            if (t + 2 < NT)      { VM6; }       // tile t+1 landed; t+2 in flight
            else if (t + 1 < NT) { VM0; }       // drain last prefetched tile
            __builtin_amdgcn_s_barrier();
            LGKM0;
            __builtin_amdgcn_s_setprio(1);
            #pragma unroll
            for (int j = 0; j < 4; ++j) {
                acc[6][j] = __builtin_amdgcn_mfma_f32_16x16x32_bf16(a0, vbh[j], acc[6][j], 0, 0, 0);
                acc[6][j] = __builtin_amdgcn_mfma_f32_16x16x32_bf16(a0, vbl[j], acc[6][j], 0, 0, 0);
                acc[7][j] = __builtin_amdgcn_mfma_f32_16x16x32_bf16(a1, vbh[j], acc[7][j], 0, 0, 0);
                acc[7][j] = __builtin_amdgcn_mfma_f32_16x16x32_bf16(a1, vbl[j], acc[7][j], 0, 0, 0);
            }
            __builtin_amdgcn_s_setprio(0);
            __builtin_amdgcn_s_barrier();
        }
        cur = (cur == 2) ? 0 : cur + 1;
        nx2 = (nx2 == 2) ? 0 : nx2 + 1;
    }

    // D: col = lane&15, row = (lane>>4)*4 + reg  (m89-verified); bf16 store
    #pragma unroll
    for (int j = 0; j < 4; ++j) {
        int col = n0 + wc * 64 + j * 16 + r;
        float bv = bias[col];
        #pragma unroll
        for (int i = 0; i < 8; ++i) {
            int rowb = m0 + wr * 128 + i * 16 + g * 4;
            #pragma unroll
            for (int t = 0; t < 4; ++t)
                C[(size_t)(rowb + t) * Nc + col] = f2bf_rn(acc[i][j][t] + bv);
        }
    }
}

// -------- XCD swizzle for edge kernels: graph g -> XCD g%8 (128 blocks/graph) --

__device__ __forceinline__ int edge_blk_swz(int blk, int swz) {
    if (swz) {
        int x = blk & 7, i = blk >> 3;
        blk = (i >> 7) * 1024 + x * 128 + (i & 127);
    }
    return blk;
}

// ---------------- Layer 1 edge kernel: wave per node, 8 ch/lane ----------------
// xlr bf16 [chunkN][1024] (xl | xr). Writes h as bf16 (Hh).

__global__ __launch_bounds__(256) void gat_edge1(
        const unsigned short* __restrict__ xlr,
        const float* __restrict__ att, const float* __restrict__ bias,
        const int* __restrict__ roff, const int* __restrict__ csrc,
        unsigned short* __restrict__ Hh, int chunkN, int n0, int swz) {
    int blk = edge_blk_swz(blockIdx.x, swz);
    int node = blk * 4 + (threadIdx.x >> 6);
    if (node >= chunkN) return;
    int lane = threadIdx.x & 63;
    int bc = lane * 8;                 // head = lane/16
    float xrv[8], attv[8];
    {
        ushort8 t0 = *(const ushort8*)&xlr[(size_t)node * 1024 + 512 + bc];
        #pragma unroll
        for (int k = 0; k < 8; ++k) xrv[k] = bf2f(t0[k]);
        float4 a0 = *(const float4*)&att[bc];
        float4 a1 = *(const float4*)&att[bc + 4];
        attv[0]=a0.x; attv[1]=a0.y; attv[2]=a0.z; attv[3]=a0.w;
        attv[4]=a1.x; attv[5]=a1.y; attv[6]=a1.z; attv[7]=a1.w;
    }
    float acc[8] = {0,0,0,0,0,0,0,0};
    float m = -3.0e38f, d = 0.0f;
    int e0 = roff[n0 + node], e1 = roff[n0 + node + 1];
    ushort8 cv;
    {
        int s = csrc[e0] - n0;
        cv = *(const ushort8*)&xlr[(size_t)s * 1024 + bc];
    }
    for (int e = e0; e < e1; ++e) {
        float xv[8];
        #pragma unroll
        for (int k = 0; k < 8; ++k) xv[k] = bf2f(cv[k]);
        if (e + 1 < e1) {              // prefetch next edge
            int s2 = csrc[e + 1] - n0;
            cv = *(const ushort8*)&xlr[(size_t)s2 * 1024 + bc];
        }
        float p = 0.0f;
        #pragma unroll
        for (int k = 0; k < 8; ++k) {
            float t = xv[k] + xrv[k];
            t = (t > 0.0f) ? t : 0.2f * t;
            p = fmaf(t, attv[k], p);
        }
        p += __shfl_xor(p, 1); p += __shfl_xor(p, 2);
        p += __shfl_xor(p, 4); p += __shfl_xor(p, 8);
        float mn = fmaxf(m, p);
        float sc = __expf(m - mn);
        float w  = __expf(p - mn);
        d = d * sc + w;
        #pragma unroll
        for (int k = 0; k < 8; ++k) acc[k] = fmaf(acc[k], sc, w * xv[k]);
        m = mn;
    }
    float inv = 1.0f / (d + 1e-16f);
    ushort8 hv;
    #pragma unroll
    for (int k = 0; k < 8; ++k)
        hv[k] = f2bf_rn(acc[k] * inv + bias[bc + k]);
    *(ushort8*)&Hh[(size_t)node * 512 + bc] = hv;
}

// ------- Layer 2 edge kernel: fused head-mean + feature-mean, xlr bf16 [N][512] --

__global__ __launch_bounds__(256) void gat_edge2(
        const unsigned short* __restrict__ xlr,
        const float* __restrict__ att, const float* __restrict__ bias,
        const int* __restrict__ roff, const int* __restrict__ csrc,
        float* __restrict__ out, int chunkN, int n0, int swz) {
    int blk = edge_blk_swz(blockIdx.x, swz);
    int node = blk * 4 + (threadIdx.x >> 6);
    if (node >= chunkN) return;
    int lane = threadIdx.x & 63;
    int bc = lane * 4;                 // within [0,256); head = lane/16
    float xrv[4], attv[4];
    {
        ushort4v t0 = *(const ushort4v*)&xlr[(size_t)node * 512 + 256 + bc];
        #pragma unroll
        for (int k = 0; k < 4; ++k) xrv[k] = bf2f(t0[k]);
        float4 a0 = *(const float4*)&att[bc];
        attv[0]=a0.x; attv[1]=a0.y; attv[2]=a0.z; attv[3]=a0.w;
    }
    float acc[4] = {0,0,0,0};
    float m = -3.0e38f, d = 0.0f;
    int e0 = roff[n0 + node], e1 = roff[n0 + node + 1];
    ushort4v cv;
    {
        int s = csrc[e0] - n0;
        cv = *(const ushort4v*)&xlr[(size_t)s * 512 + bc];
    }
    for (int e = e0; e < e1; ++e) {
        float xv[4];
        #pragma unroll
        for (int k = 0; k < 4; ++k) xv[k] = bf2f(cv[k]);
        if (e + 1 < e1) {
            int s2 = csrc[e + 1] - n0;
            cv = *(const ushort4v*)&xlr[(size_t)s2 * 512 + bc];
        }
        float p = 0.0f;
        #pragma unroll
        for (int k = 0; k < 4; ++k) {
            float t = xv[k] + xrv[k];
            t = (t > 0.0f) ? t : 0.2f * t;
            p = fmaf(t, attv[k], p);
        }
        p += __shfl_xor(p, 1); p += __shfl_xor(p, 2);
        p += __shfl_xor(p, 4); p += __shfl_xor(p, 8);
        float mn = fmaxf(m, p);
        float sc = __expf(m - mn);
        float w  = __expf(p - mn);
        d = d * sc + w;
        #pragma unroll
        for (int k = 0; k < 4; ++k) acc[k] = fmaf(acc[k], sc, w * xv[k]);
        m = mn;
    }
    float inv = 1.0f / (d + 1e-16f);
    float v[4];
    #pragma unroll
    for (int k = 0; k < 4; ++k) v[k] = acc[k] * inv;
    #pragma unroll
    for (int k = 0; k < 4; ++k) {
        v[k] += __shfl_xor(v[k], 16);
        v[k] += __shfl_xor(v[k], 32);
    }
    int cb = (lane & 15) * 4;
    float s = 0.25f * (v[0] + v[1] + v[2] + v[3])
            + bias[cb] + bias[cb + 1] + bias[cb + 2] + bias[cb + 3];
    s += __shfl_xor(s, 1); s += __shfl_xor(s, 2);
    s += __shfl_xor(s, 4); s += __shfl_xor(s, 8);
    if (lane == 0) out[node] = s * (1.0f / 64.0f);
}

// ---------------- launch ----------------

extern "C" void kernel_launch(void* const* d_in, const int* in_sizes, int n_in,
                              void* d_out, int out_size, void* d_ws, size_t ws_size,
                              hipStream_t stream) {
    const float* x    = (const float*)d_in[0];
    const int*   ei   = (const int*)d_in[1];
    const float* Wl1  = (const float*)d_in[3];
    const float* bl1  = (const float*)d_in[4];
    const float* Wr1  = (const float*)d_in[5];
    const float* br1  = (const float*)d_in[6];
    const float* att1 = (const float*)d_in[7];
    const float* bias1= (const float*)d_in[8];
    const float* Wl2  = (const float*)d_in[9];
    const float* bl2  = (const float*)d_in[10];
    const float* Wr2  = (const float*)d_in[11];
    const float* br2  = (const float*)d_in[12];
    const float* att2 = (const float*)d_in[13];
    const float* bias2= (const float*)d_in[14];
    float* out = (float*)d_out;

    const int F = 512;
    const int N = in_sizes[0] / F;        // 32768
    const int E = in_sizes[1] / 2;        // 262144
    const int NG = 64;
    const int NPG = N / NG;               // 512
    const int EPG = E / NG + NPG;         // 4608

    char* w = (char*)d_ws;
    int* roff = (int*)(w);
    int* cnt  = (int*)(w + 0x40000);
    int* csrc = (int*)(w + 0x80000);
    unsigned short* wc1h = (unsigned short*)(w + 0x200000);
    unsigned short* wc1l = (unsigned short*)(w + 0x300000);
    unsigned short* wc2h = (unsigned short*)(w + 0x400000);
    unsigned short* wc2l = (unsigned short*)(w + 0x480000);
    float* bcat1 = (float*)(w + 0x500000);
    float* bcat2 = (float*)(w + 0x501000);
    const size_t HDR = 6ull << 20;

    int chunkG = NG;
    while (chunkG > 1) {
        size_t need = HDR + 3ull * (size_t)chunkG * NPG * 512 * 4;
        if (need <= ws_size) break;
        chunkG >>= 1;
    }
    const int chunkN = chunkG * NPG;
    const size_t BSZ = (size_t)chunkN * 512 * 4;
    char* R1 = w + HDR;
    char* R2 = w + HDR + BSZ;
    const int swz = (chunkG % 8 == 0) ? 1 : 0;

    hipMemsetAsync(cnt, 0, (size_t)N * 4, stream);
    hist_kernel<<<1024, 256, 0, stream>>>(ei, E, N, cnt);
    scan_pg<<<NG, 512, 0, stream>>>(cnt, roff, NPG, EPG);
    hipMemsetAsync(cnt, 0, (size_t)N * 4, stream);
    scatter_kernel<<<1024, 256, 0, stream>>>(ei, E, N, roff, cnt, csrc);

    tdecomp_kernel<<<dim3(512/32, 512/32), 256, 0, stream>>>(Wl1, wc1h, wc1l, 512, 512);
    tdecomp_kernel<<<dim3(512/32, 512/32), 256, 0, stream>>>(Wr1, wc1h + 512*512, wc1l + 512*512, 512, 512);
    tdecomp_kernel<<<dim3(256/32, 512/32), 256, 0, stream>>>(Wl2, wc2h, wc2l, 512, 256);
    tdecomp_kernel<<<dim3(256/32, 512/32), 256, 0, stream>>>(Wr2, wc2h + 256*512, wc2l + 256*512, 512, 256);
    hipMemcpyAsync(bcat1,       bl1, 512 * 4, hipMemcpyDeviceToDevice, stream);
    hipMemcpyAsync(bcat1 + 512, br1, 512 * 4, hipMemcpyDeviceToDevice, stream);
    hipMemcpyAsync(bcat2,       bl2, 256 * 4, hipMemcpyDeviceToDevice, stream);
    hipMemcpyAsync(bcat2 + 256, br2, 256 * 4, hipMemcpyDeviceToDevice, stream);

    for (int g0 = 0; g0 < NG; g0 += chunkG) {
        int n0 = g0 * NPG;
        const float* xc = x + (size_t)n0 * 512;
        unsigned short* Xh   = (unsigned short*)R1;
        unsigned short* xlr1 = (unsigned short*)R2;  // bf16 [chunkN][1024]
        unsigned short* Hh   = (unsigned short*)R1;  // reuse (Xh dead after L1 gemm)
        unsigned short* xlr2 = (unsigned short*)R2;  // bf16 [chunkN][512]

        cast_hi_kernel<<<2048, 256, 0, stream>>>(xc, Xh, chunkN * 512 / 4);
        gemm256p8<<<dim3(1024/256, chunkN/256), 512, 0, stream>>>(
            Xh, wc1h, wc1l, bcat1, xlr1, chunkN, 512, 1024);
        gat_edge1<<<(chunkN * 64) / 256, 256, 0, stream>>>(
            xlr1, att1, bias1, roff, csrc, Hh, chunkN, n0, swz);

        gemm256p8<<<dim3(512/256, chunkN/256), 512, 0, stream>>>(
            Hh, wc2h, wc2l, bcat2, xlr2, chunkN, 512, 512);
        gat_edge2<<<(chunkN * 64) / 256, 256, 0, stream>>>(
            xlr2, att2, bias2, roff, csrc, out + n0, chunkN, n0, swz);
    }
}

// Round 14
// 248.327 us; speedup vs baseline: 1.0363x; 1.0363x over previous
//
#include <hip/hip_runtime.h>
#include <hip/hip_bf16.h>

// GATv2 2-layer GNN. Round 14: GEMM back to 128x128 tile / 4 waves / 48KB LDS
// (3 blocks/CU -> implicit inter-block overlap, the m114 mechanism) combined
// with 2-product split (round 10) and bf16 activations (round 12).
// N=32768 (64 graphs x 512), F=512, E=262144 (+N self loops), H=4, C1=128, C2=64.

typedef __bf16 bf16_t;
typedef bf16_t bf16x8 __attribute__((ext_vector_type(8)));
typedef float f32x4 __attribute__((ext_vector_type(4)));
typedef unsigned short ushort8 __attribute__((ext_vector_type(8)));
typedef unsigned short ushort4v __attribute__((ext_vector_type(4)));

__device__ __forceinline__ unsigned short f2bf_rn(float f) {
    unsigned u = __float_as_uint(f);
    unsigned r = (u + 0x7FFFu + ((u >> 16) & 1u)) >> 16;
    return (unsigned short)r;
}
__device__ __forceinline__ float bf2f(unsigned short h) {
    return __uint_as_float((unsigned)h << 16);
}

// ---------------- CSR build ----------------

__global__ void hist_kernel(const int* __restrict__ ei, int E, int N,
                            int* __restrict__ deg) {
    int total = E + N;
    for (int e = blockIdx.x * blockDim.x + threadIdx.x; e < total;
         e += gridDim.x * blockDim.x) {
        int dst = (e < E) ? ei[E + e] : (e - E);
        atomicAdd(&deg[dst], 1);
    }
}

__global__ __launch_bounds__(512) void scan_pg(const int* __restrict__ deg,
                                               int* __restrict__ off,
                                               int NPG, int EPG) {
    __shared__ int buf[512];
    int g = blockIdx.x, tid = threadIdx.x;
    int base = g * NPG;
    buf[tid] = deg[base + tid];
    __syncthreads();
    #pragma unroll
    for (int ofs = 1; ofs < 512; ofs <<= 1) {
        int t = (tid >= ofs) ? buf[tid - ofs] : 0;
        __syncthreads();
        buf[tid] += t;
        __syncthreads();
    }
    off[base + tid + 1] = g * EPG + buf[tid];
    if (tid == 0) off[base] = g * EPG;
}

__global__ void scatter_kernel(const int* __restrict__ ei, int E, int N,
                               const int* __restrict__ off, int* __restrict__ cnt,
                               int* __restrict__ csrc) {
    int total = E + N;
    for (int e = blockIdx.x * blockDim.x + threadIdx.x; e < total;
         e += gridDim.x * blockDim.x) {
        int src, dst;
        if (e < E) { src = ei[e]; dst = ei[E + e]; }
        else       { src = e - E; dst = e - E; }
        int pos = off[dst] + atomicAdd(&cnt[dst], 1);
        csrc[pos] = src;
    }
}

// ---------------- fp32 -> bf16 cast (hi only) ----------------

__global__ __launch_bounds__(256) void cast_hi_kernel(
        const float* __restrict__ X, unsigned short* __restrict__ hi, int n4) {
    for (int i = blockIdx.x * blockDim.x + threadIdx.x; i < n4;
         i += gridDim.x * blockDim.x) {
        float4 v = ((const float4*)X)[i];
        ushort4 h;
        h.x = f2bf_rn(v.x); h.y = f2bf_rn(v.y);
        h.z = f2bf_rn(v.z); h.w = f2bf_rn(v.w);
        ((ushort4*)hi)[i] = h;
    }
}

// W [K][Nc] fp32 -> Wt hi/lo [Nc][K] bf16 (transpose + decompose)
__global__ __launch_bounds__(256) void tdecomp_kernel(
        const float* __restrict__ W, unsigned short* __restrict__ th,
        unsigned short* __restrict__ tl, int K, int Nc) {
    __shared__ float t[32][33];
    int bx = blockIdx.x, by = blockIdx.y;
    int lx = threadIdx.x & 31, ly = threadIdx.x >> 5;
    #pragma unroll
    for (int r = ly; r < 32; r += 8)
        t[r][lx] = W[(size_t)(by * 32 + r) * Nc + bx * 32 + lx];
    __syncthreads();
    #pragma unroll
    for (int r = ly; r < 32; r += 8) {
        float v = t[lx][r];
        unsigned short hb = f2bf_rn(v);
        float hf = __uint_as_float((unsigned)hb << 16);
        unsigned short lb = f2bf_rn(v - hf);
        size_t o = (size_t)(bx * 32 + r) * K + by * 32 + lx;
        th[o] = hb; tl[o] = lb;
    }
}

// ---- 128x128 GEMM, 4 waves, 2-product, 2-buffer dbuf (48KB -> 3 blk/CU) ----
// C(bf16) = A@(Bh+Bl)^T + bias. Bt [Nc][K]; BK=32. Round-8 structure.
// Conflict-free slot swizzle: physical 16B-slot = logical ^ ((row>>1)&3).

__global__ __launch_bounds__(256) void gemm128b(
        const unsigned short* __restrict__ A,
        const unsigned short* __restrict__ Bh, const unsigned short* __restrict__ Bl,
        const float* __restrict__ bias, unsigned short* __restrict__ C,
        int M, int K, int Nc) {
    constexpr int NQ  = 6;
    constexpr int BUF = 24576;                  // A|Bh|Bl tiles, 8KB each
    __shared__ __align__(16) char smem[2 * BUF];

    int tid  = threadIdx.x;
    int wave = tid >> 6, lane = tid & 63;
    int wr = wave >> 1, wc = wave & 1;          // 2x2 waves, 64x64 per wave

    int bx = blockIdx.x, by = blockIdx.y;
    if ((gridDim.y & 7) == 0) {                 // XCD swizzle: A-panel -> one XCD
        int d = blockIdx.y * gridDim.x + blockIdx.x;
        int x = d & 7, i = d >> 3;
        by = (i / gridDim.x) * 8 + x;
        bx = i % gridDim.x;
    }
    int m0 = by * 128, n0 = bx * 128;

    const unsigned short* gsrc[NQ];
    int loff[NQ];
    #pragma unroll
    for (int q = 0; q < NQ; ++q) {
        int o    = q * 4096 + tid * 16;
        int tile = o >> 13;
        int ot   = o & 8191;
        int row  = ot >> 6;
        int slot = (ot >> 4) & 3;
        int sl   = slot ^ ((row >> 1) & 3);     // conflict-free involution
        const unsigned short* base =
            (tile == 0) ? (A  + (size_t)(m0 + row) * K) :
            (tile == 1) ? (Bh + (size_t)(n0 + row) * K) :
                          (Bl + (size_t)(n0 + row) * K);
        gsrc[q] = base + sl * 8;
        loff[q] = q * 4096 + wave * 1024;       // wave-uniform dest + lane*16
    }

    f32x4 acc[4][4];
    #pragma unroll
    for (int i = 0; i < 4; ++i)
        #pragma unroll
        for (int j = 0; j < 4; ++j) acc[i][j] = (f32x4){0.f, 0.f, 0.f, 0.f};

    int r = lane & 15, g = lane >> 4;
    int sw = (g ^ ((r >> 1) & 3)) * 16;         // matching read-side key

    #pragma unroll
    for (int q = 0; q < NQ; ++q) {
        __builtin_amdgcn_global_load_lds(
            (const __attribute__((address_space(1))) void*)(gsrc[q]),
            (__attribute__((address_space(3))) void*)(smem + loff[q]), 16, 0, 0);
        gsrc[q] += 32;
    }
    __syncthreads();

    const int NT = K >> 5;
    int cur = 0;
    for (int t = 0; t < NT; ++t) {
        if (t + 1 < NT) {                       // issue next tile EARLY
            #pragma unroll
            for (int q = 0; q < NQ; ++q) {
                __builtin_amdgcn_global_load_lds(
                    (const __attribute__((address_space(1))) void*)(gsrc[q]),
                    (__attribute__((address_space(3))) void*)(smem + loff[q] + (cur ^ BUF)),
                    16, 0, 0);
                gsrc[q] += 32;
            }
        }
        const char* sb = smem + cur;
        bf16x8 a[4], bh[4], bl[4];
        #pragma unroll
        for (int i = 0; i < 4; ++i) {
            int offA = (wr * 64 + i * 16 + r) * 64 + sw;
            int offB = (wc * 64 + i * 16 + r) * 64 + sw;
            a[i]  = *(const bf16x8*)(sb + offA);
            bh[i] = *(const bf16x8*)(sb + 8192 + offB);
            bl[i] = *(const bf16x8*)(sb + 16384 + offB);
        }
        __builtin_amdgcn_s_setprio(1);
        #pragma unroll
        for (int i = 0; i < 4; ++i)
            #pragma unroll
            for (int j = 0; j < 4; ++j) {
                acc[i][j] = __builtin_amdgcn_mfma_f32_16x16x32_bf16(a[i], bh[j], acc[i][j], 0, 0, 0);
                acc[i][j] = __builtin_amdgcn_mfma_f32_16x16x32_bf16(a[i], bl[j], acc[i][j], 0, 0, 0);
            }
        __builtin_amdgcn_s_setprio(0);
        __syncthreads();
        cur ^= BUF;
    }

    // D: col = lane&15, row = (lane>>4)*4 + reg  (m89-verified); bf16 store
    #pragma unroll
    for (int j = 0; j < 4; ++j) {
        int col = n0 + wc * 64 + j * 16 + r;
        float bv = bias[col];
        #pragma unroll
        for (int i = 0; i < 4; ++i) {
            int rowb = m0 + wr * 64 + i * 16 + g * 4;
            #pragma unroll
            for (int t = 0; t < 4; ++t)
                C[(size_t)(rowb + t) * Nc + col] = f2bf_rn(acc[i][j][t] + bv);
        }
    }
}

// -------- XCD swizzle for edge kernels: graph g -> XCD g%8 (128 blocks/graph) --

__device__ __forceinline__ int edge_blk_swz(int blk, int swz) {
    if (swz) {
        int x = blk & 7, i = blk >> 3;
        blk = (i >> 7) * 1024 + x * 128 + (i & 127);
    }
    return blk;
}

// ---------------- Layer 1 edge kernel: wave per node, 8 ch/lane ----------------
// xlr bf16 [chunkN][1024] (xl | xr). Writes h as bf16 (Hh).

__global__ __launch_bounds__(256) void gat_edge1(
        const unsigned short* __restrict__ xlr,
        const float* __restrict__ att, const float* __restrict__ bias,
        const int* __restrict__ roff, const int* __restrict__ csrc,
        unsigned short* __restrict__ Hh, int chunkN, int n0, int swz) {
    int blk = edge_blk_swz(blockIdx.x, swz);
    int node = blk * 4 + (threadIdx.x >> 6);
    if (node >= chunkN) return;
    int lane = threadIdx.x & 63;
    int bc = lane * 8;                 // head = lane/16
    float xrv[8], attv[8];
    {
        ushort8 t0 = *(const ushort8*)&xlr[(size_t)node * 1024 + 512 + bc];
        #pragma unroll
        for (int k = 0; k < 8; ++k) xrv[k] = bf2f(t0[k]);
        float4 a0 = *(const float4*)&att[bc];
        float4 a1 = *(const float4*)&att[bc + 4];
        attv[0]=a0.x; attv[1]=a0.y; attv[2]=a0.z; attv[3]=a0.w;
        attv[4]=a1.x; attv[5]=a1.y; attv[6]=a1.z; attv[7]=a1.w;
    }
    float acc[8] = {0,0,0,0,0,0,0,0};
    float m = -3.0e38f, d = 0.0f;
    int e0 = roff[n0 + node], e1 = roff[n0 + node + 1];
    ushort8 cv;
    {
        int s = csrc[e0] - n0;
        cv = *(const ushort8*)&xlr[(size_t)s * 1024 + bc];
    }
    for (int e = e0; e < e1; ++e) {
        float xv[8];
        #pragma unroll
        for (int k = 0; k < 8; ++k) xv[k] = bf2f(cv[k]);
        if (e + 1 < e1) {              // prefetch next edge
            int s2 = csrc[e + 1] - n0;
            cv = *(const ushort8*)&xlr[(size_t)s2 * 1024 + bc];
        }
        float p = 0.0f;
        #pragma unroll
        for (int k = 0; k < 8; ++k) {
            float t = xv[k] + xrv[k];
            t = (t > 0.0f) ? t : 0.2f * t;
            p = fmaf(t, attv[k], p);
        }
        p += __shfl_xor(p, 1); p += __shfl_xor(p, 2);
        p += __shfl_xor(p, 4); p += __shfl_xor(p, 8);
        float mn = fmaxf(m, p);
        float sc = __expf(m - mn);
        float w  = __expf(p - mn);
        d = d * sc + w;
        #pragma unroll
        for (int k = 0; k < 8; ++k) acc[k] = fmaf(acc[k], sc, w * xv[k]);
        m = mn;
    }
    float inv = 1.0f / (d + 1e-16f);
    ushort8 hv;
    #pragma unroll
    for (int k = 0; k < 8; ++k)
        hv[k] = f2bf_rn(acc[k] * inv + bias[bc + k]);
    *(ushort8*)&Hh[(size_t)node * 512 + bc] = hv;
}

// ------- Layer 2 edge kernel: fused head-mean + feature-mean, xlr bf16 [N][512] --

__global__ __launch_bounds__(256) void gat_edge2(
        const unsigned short* __restrict__ xlr,
        const float* __restrict__ att, const float* __restrict__ bias,
        const int* __restrict__ roff, const int* __restrict__ csrc,
        float* __restrict__ out, int chunkN, int n0, int swz) {
    int blk = edge_blk_swz(blockIdx.x, swz);
    int node = blk * 4 + (threadIdx.x >> 6);
    if (node >= chunkN) return;
    int lane = threadIdx.x & 63;
    int bc = lane * 4;                 // within [0,256); head = lane/16
    float xrv[4], attv[4];
    {
        ushort4v t0 = *(const ushort4v*)&xlr[(size_t)node * 512 + 256 + bc];
        #pragma unroll
        for (int k = 0; k < 4; ++k) xrv[k] = bf2f(t0[k]);
        float4 a0 = *(const float4*)&att[bc];
        attv[0]=a0.x; attv[1]=a0.y; attv[2]=a0.z; attv[3]=a0.w;
    }
    float acc[4] = {0,0,0,0};
    float m = -3.0e38f, d = 0.0f;
    int e0 = roff[n0 + node], e1 = roff[n0 + node + 1];
    ushort4v cv;
    {
        int s = csrc[e0] - n0;
        cv = *(const ushort4v*)&xlr[(size_t)s * 512 + bc];
    }
    for (int e = e0; e < e1; ++e) {
        float xv[4];
        #pragma unroll
        for (int k = 0; k < 4; ++k) xv[k] = bf2f(cv[k]);
        if (e + 1 < e1) {
            int s2 = csrc[e + 1] - n0;
            cv = *(const ushort4v*)&xlr[(size_t)s2 * 512 + bc];
        }
        float p = 0.0f;
        #pragma unroll
        for (int k = 0; k < 4; ++k) {
            float t = xv[k] + xrv[k];
            t = (t > 0.0f) ? t : 0.2f * t;
            p = fmaf(t, attv[k], p);
        }
        p += __shfl_xor(p, 1); p += __shfl_xor(p, 2);
        p += __shfl_xor(p, 4); p += __shfl_xor(p, 8);
        float mn = fmaxf(m, p);
        float sc = __expf(m - mn);
        float w  = __expf(p - mn);
        d = d * sc + w;
        #pragma unroll
        for (int k = 0; k < 4; ++k) acc[k] = fmaf(acc[k], sc, w * xv[k]);
        m = mn;
    }
    float inv = 1.0f / (d + 1e-16f);
    float v[4];
    #pragma unroll
    for (int k = 0; k < 4; ++k) v[k] = acc[k] * inv;
    #pragma unroll
    for (int k = 0; k < 4; ++k) {
        v[k] += __shfl_xor(v[k], 16);
        v[k] += __shfl_xor(v[k], 32);
    }
    int cb = (lane & 15) * 4;
    float s = 0.25f * (v[0] + v[1] + v[2] + v[3])
            + bias[cb] + bias[cb + 1] + bias[cb + 2] + bias[cb + 3];
    s += __shfl_xor(s, 1); s += __shfl_xor(s, 2);
    s += __shfl_xor(s, 4); s += __shfl_xor(s, 8);
    if (lane == 0) out[node] = s * (1.0f / 64.0f);
}

// ---------------- launch ----------------

extern "C" void kernel_launch(void* const* d_in, const int* in_sizes, int n_in,
                              void* d_out, int out_size, void* d_ws, size_t ws_size,
                              hipStream_t stream) {
    const float* x    = (const float*)d_in[0];
    const int*   ei   = (const int*)d_in[1];
    const float* Wl1  = (const float*)d_in[3];
    const float* bl1  = (const float*)d_in[4];
    const float* Wr1  = (const float*)d_in[5];
    const float* br1  = (const float*)d_in[6];
    const float* att1 = (const float*)d_in[7];
    const float* bias1= (const float*)d_in[8];
    const float* Wl2  = (const float*)d_in[9];
    const float* bl2  = (const float*)d_in[10];
    const float* Wr2  = (const float*)d_in[11];
    const float* br2  = (const float*)d_in[12];
    const float* att2 = (const float*)d_in[13];
    const float* bias2= (const float*)d_in[14];
    float* out = (float*)d_out;

    const int F = 512;
    const int N = in_sizes[0] / F;        // 32768
    const int E = in_sizes[1] / 2;        // 262144
    const int NG = 64;
    const int NPG = N / NG;               // 512
    const int EPG = E / NG + NPG;         // 4608

    char* w = (char*)d_ws;
    int* roff = (int*)(w);
    int* cnt  = (int*)(w + 0x40000);
    int* csrc = (int*)(w + 0x80000);
    unsigned short* wc1h = (unsigned short*)(w + 0x200000);
    unsigned short* wc1l = (unsigned short*)(w + 0x300000);
    unsigned short* wc2h = (unsigned short*)(w + 0x400000);
    unsigned short* wc2l = (unsigned short*)(w + 0x480000);
    float* bcat1 = (float*)(w + 0x500000);
    float* bcat2 = (float*)(w + 0x501000);
    const size_t HDR = 6ull << 20;

    int chunkG = NG;
    while (chunkG > 1) {
        size_t need = HDR + 3ull * (size_t)chunkG * NPG * 512 * 4;
        if (need <= ws_size) break;
        chunkG >>= 1;
    }
    const int chunkN = chunkG * NPG;
    const size_t BSZ = (size_t)chunkN * 512 * 4;
    char* R1 = w + HDR;
    char* R2 = w + HDR + BSZ;
    const int swz = (chunkG % 8 == 0) ? 1 : 0;

    hipMemsetAsync(cnt, 0, (size_t)N * 4, stream);
    hist_kernel<<<1024, 256, 0, stream>>>(ei, E, N, cnt);
    scan_pg<<<NG, 512, 0, stream>>>(cnt, roff, NPG, EPG);
    hipMemsetAsync(cnt, 0, (size_t)N * 4, stream);
    scatter_kernel<<<1024, 256, 0, stream>>>(ei, E, N, roff, cnt, csrc);

    tdecomp_kernel<<<dim3(512/32, 512/32), 256, 0, stream>>>(Wl1, wc1h, wc1l, 512, 512);
    tdecomp_kernel<<<dim3(512/32, 512/32), 256, 0, stream>>>(Wr1, wc1h + 512*512, wc1l + 512*512, 512, 512);
    tdecomp_kernel<<<dim3(256/32, 512/32), 256, 0, stream>>>(Wl2, wc2h, wc2l, 512, 256);
    tdecomp_kernel<<<dim3(256/32, 512/32), 256, 0, stream>>>(Wr2, wc2h + 256*512, wc2l + 256*512, 512, 256);
    hipMemcpyAsync(bcat1,       bl1, 512 * 4, hipMemcpyDeviceToDevice, stream);
    hipMemcpyAsync(bcat1 + 512, br1, 512 * 4, hipMemcpyDeviceToDevice, stream);
    hipMemcpyAsync(bcat2,       bl2, 256 * 4, hipMemcpyDeviceToDevice, stream);
    hipMemcpyAsync(bcat2 + 256, br2, 256 * 4, hipMemcpyDeviceToDevice, stream);

    for (int g0 = 0; g0 < NG; g0 += chunkG) {
        int n0 = g0 * NPG;
        const float* xc = x + (size_t)n0 * 512;
        unsigned short* Xh   = (unsigned short*)R1;
        unsigned short* xlr1 = (unsigned short*)R2;  // bf16 [chunkN][1024]
        unsigned short* Hh   = (unsigned short*)R1;  // reuse (Xh dead after L1 gemm)
        unsigned short* xlr2 = (unsigned short*)R2;  // bf16 [chunkN][512]

        cast_hi_kernel<<<2048, 256, 0, stream>>>(xc, Xh, chunkN * 512 / 4);
        gemm128b<<<dim3(1024/128, chunkN/128), 256, 0, stream>>>(
            Xh, wc1h, wc1l, bcat1, xlr1, chunkN, 512, 1024);
        gat_edge1<<<(chunkN * 64) / 256, 256, 0, stream>>>(
            xlr1, att1, bias1, roff, csrc, Hh, chunkN, n0, swz);

        gemm128b<<<dim3(512/128, chunkN/128), 256, 0, stream>>>(
            Hh, wc2h, wc2l, bcat2, xlr2, chunkN, 512, 512);
        gat_edge2<<<(chunkN * 64) / 256, 256, 0, stream>>>(
            xlr2, att2, bias2, roff, csrc, out + n0, chunkN, n0, swz);
    }
}

// Round 15
// 214.333 us; speedup vs baseline: 1.2007x; 1.1586x over previous
//
#include <hip/hip_runtime.h>
#include <hip/hip_bf16.h>

// GATv2 2-layer GNN. Round 15: pure bf16 GEMM (drop B-side lo residual) ->
// half the MFMAs again; LDS 2x16KB -> 5 blocks/CU. Calibrated error budget:
// each operand bf16-rounding adds ~1e-4 absmax (measured r8, r10); predict
// ~5e-4 total vs 1.025e-3 threshold. All else = round 14.
// N=32768 (64 graphs x 512), F=512, E=262144 (+N self loops), H=4, C1=128, C2=64.

typedef __bf16 bf16_t;
typedef bf16_t bf16x8 __attribute__((ext_vector_type(8)));
typedef float f32x4 __attribute__((ext_vector_type(4)));
typedef unsigned short ushort8 __attribute__((ext_vector_type(8)));
typedef unsigned short ushort4v __attribute__((ext_vector_type(4)));

__device__ __forceinline__ unsigned short f2bf_rn(float f) {
    unsigned u = __float_as_uint(f);
    unsigned r = (u + 0x7FFFu + ((u >> 16) & 1u)) >> 16;
    return (unsigned short)r;
}
__device__ __forceinline__ float bf2f(unsigned short h) {
    return __uint_as_float((unsigned)h << 16);
}

// ---------------- CSR build ----------------

__global__ void hist_kernel(const int* __restrict__ ei, int E, int N,
                            int* __restrict__ deg) {
    int total = E + N;
    for (int e = blockIdx.x * blockDim.x + threadIdx.x; e < total;
         e += gridDim.x * blockDim.x) {
        int dst = (e < E) ? ei[E + e] : (e - E);
        atomicAdd(&deg[dst], 1);
    }
}

__global__ __launch_bounds__(512) void scan_pg(const int* __restrict__ deg,
                                               int* __restrict__ off,
                                               int NPG, int EPG) {
    __shared__ int buf[512];
    int g = blockIdx.x, tid = threadIdx.x;
    int base = g * NPG;
    buf[tid] = deg[base + tid];
    __syncthreads();
    #pragma unroll
    for (int ofs = 1; ofs < 512; ofs <<= 1) {
        int t = (tid >= ofs) ? buf[tid - ofs] : 0;
        __syncthreads();
        buf[tid] += t;
        __syncthreads();
    }
    off[base + tid + 1] = g * EPG + buf[tid];
    if (tid == 0) off[base] = g * EPG;
}

__global__ void scatter_kernel(const int* __restrict__ ei, int E, int N,
                               const int* __restrict__ off, int* __restrict__ cnt,
                               int* __restrict__ csrc) {
    int total = E + N;
    for (int e = blockIdx.x * blockDim.x + threadIdx.x; e < total;
         e += gridDim.x * blockDim.x) {
        int src, dst;
        if (e < E) { src = ei[e]; dst = ei[E + e]; }
        else       { src = e - E; dst = e - E; }
        int pos = off[dst] + atomicAdd(&cnt[dst], 1);
        csrc[pos] = src;
    }
}

// ---------------- fp32 -> bf16 cast (hi only) ----------------

__global__ __launch_bounds__(256) void cast_hi_kernel(
        const float* __restrict__ X, unsigned short* __restrict__ hi, int n4) {
    for (int i = blockIdx.x * blockDim.x + threadIdx.x; i < n4;
         i += gridDim.x * blockDim.x) {
        float4 v = ((const float4*)X)[i];
        ushort4 h;
        h.x = f2bf_rn(v.x); h.y = f2bf_rn(v.y);
        h.z = f2bf_rn(v.z); h.w = f2bf_rn(v.w);
        ((ushort4*)hi)[i] = h;
    }
}

// W [K][Nc] fp32 -> Wt [Nc][K] bf16 (transpose + round-to-nearest cast)
__global__ __launch_bounds__(256) void tcast_kernel(
        const float* __restrict__ W, unsigned short* __restrict__ th,
        int K, int Nc) {
    __shared__ float t[32][33];
    int bx = blockIdx.x, by = blockIdx.y;
    int lx = threadIdx.x & 31, ly = threadIdx.x >> 5;
    #pragma unroll
    for (int r = ly; r < 32; r += 8)
        t[r][lx] = W[(size_t)(by * 32 + r) * Nc + bx * 32 + lx];
    __syncthreads();
    #pragma unroll
    for (int r = ly; r < 32; r += 8)
        th[(size_t)(bx * 32 + r) * K + by * 32 + lx] = f2bf_rn(t[lx][r]);
}

// ---- 128x128 GEMM, 4 waves, pure bf16, 2-buffer dbuf (32KB -> 5 blk/CU) ----
// C(bf16) = A@B^T + bias. Bt [Nc][K]; BK=32.
// Conflict-free slot swizzle: physical 16B-slot = logical ^ ((row>>1)&3).

__global__ __launch_bounds__(256) void gemm128b(
        const unsigned short* __restrict__ A,
        const unsigned short* __restrict__ B,
        const float* __restrict__ bias, unsigned short* __restrict__ C,
        int M, int K, int Nc) {
    constexpr int NQ  = 4;
    constexpr int BUF = 16384;                  // A|B tiles, 8KB each
    __shared__ __align__(16) char smem[2 * BUF];

    int tid  = threadIdx.x;
    int wave = tid >> 6, lane = tid & 63;
    int wr = wave >> 1, wc = wave & 1;          // 2x2 waves, 64x64 per wave

    int bx = blockIdx.x, by = blockIdx.y;
    if ((gridDim.y & 7) == 0) {                 // XCD swizzle: A-panel -> one XCD
        int d = blockIdx.y * gridDim.x + blockIdx.x;
        int x = d & 7, i = d >> 3;
        by = (i / gridDim.x) * 8 + x;
        bx = i % gridDim.x;
    }
    int m0 = by * 128, n0 = bx * 128;

    const unsigned short* gsrc[NQ];
    int loff[NQ];
    #pragma unroll
    for (int q = 0; q < NQ; ++q) {
        int o    = q * 4096 + tid * 16;
        int tile = o >> 13;                     // 0 = A, 1 = B
        int ot   = o & 8191;
        int row  = ot >> 6;
        int slot = (ot >> 4) & 3;
        int sl   = slot ^ ((row >> 1) & 3);     // conflict-free involution
        const unsigned short* base =
            (tile == 0) ? (A + (size_t)(m0 + row) * K)
                        : (B + (size_t)(n0 + row) * K);
        gsrc[q] = base + sl * 8;
        loff[q] = q * 4096 + wave * 1024;       // wave-uniform dest + lane*16
    }

    f32x4 acc[4][4];
    #pragma unroll
    for (int i = 0; i < 4; ++i)
        #pragma unroll
        for (int j = 0; j < 4; ++j) acc[i][j] = (f32x4){0.f, 0.f, 0.f, 0.f};

    int r = lane & 15, g = lane >> 4;
    int sw = (g ^ ((r >> 1) & 3)) * 16;         // matching read-side key

    #pragma unroll
    for (int q = 0; q < NQ; ++q) {
        __builtin_amdgcn_global_load_lds(
            (const __attribute__((address_space(1))) void*)(gsrc[q]),
            (__attribute__((address_space(3))) void*)(smem + loff[q]), 16, 0, 0);
        gsrc[q] += 32;
    }
    __syncthreads();

    const int NT = K >> 5;
    int cur = 0;
    for (int t = 0; t < NT; ++t) {
        if (t + 1 < NT) {                       // issue next tile EARLY
            #pragma unroll
            for (int q = 0; q < NQ; ++q) {
                __builtin_amdgcn_global_load_lds(
                    (const __attribute__((address_space(1))) void*)(gsrc[q]),
                    (__attribute__((address_space(3))) void*)(smem + loff[q] + (cur ^ BUF)),
                    16, 0, 0);
                gsrc[q] += 32;
            }
        }
        const char* sb = smem + cur;
        bf16x8 a[4], b[4];
        #pragma unroll
        for (int i = 0; i < 4; ++i) {
            int offA = (wr * 64 + i * 16 + r) * 64 + sw;
            int offB = (wc * 64 + i * 16 + r) * 64 + sw;
            a[i] = *(const bf16x8*)(sb + offA);
            b[i] = *(const bf16x8*)(sb + 8192 + offB);
        }
        __builtin_amdgcn_s_setprio(1);
        #pragma unroll
        for (int i = 0; i < 4; ++i)
            #pragma unroll
            for (int j = 0; j < 4; ++j)
                acc[i][j] = __builtin_amdgcn_mfma_f32_16x16x32_bf16(a[i], b[j], acc[i][j], 0, 0, 0);
        __builtin_amdgcn_s_setprio(0);
        __syncthreads();
        cur ^= BUF;
    }

    // D: col = lane&15, row = (lane>>4)*4 + reg  (m89-verified); bf16 store
    #pragma unroll
    for (int j = 0; j < 4; ++j) {
        int col = n0 + wc * 64 + j * 16 + r;
        float bv = bias[col];
        #pragma unroll
        for (int i = 0; i < 4; ++i) {
            int rowb = m0 + wr * 64 + i * 16 + g * 4;
            #pragma unroll
            for (int t = 0; t < 4; ++t)
                C[(size_t)(rowb + t) * Nc + col] = f2bf_rn(acc[i][j][t] + bv);
        }
    }
}

// -------- XCD swizzle for edge kernels: graph g -> XCD g%8 (128 blocks/graph) --

__device__ __forceinline__ int edge_blk_swz(int blk, int swz) {
    if (swz) {
        int x = blk & 7, i = blk >> 3;
        blk = (i >> 7) * 1024 + x * 128 + (i & 127);
    }
    return blk;
}

// ---------------- Layer 1 edge kernel: wave per node, 8 ch/lane ----------------
// xlr bf16 [chunkN][1024] (xl | xr). Writes h as bf16 (Hh).

__global__ __launch_bounds__(256) void gat_edge1(
        const unsigned short* __restrict__ xlr,
        const float* __restrict__ att, const float* __restrict__ bias,
        const int* __restrict__ roff, const int* __restrict__ csrc,
        unsigned short* __restrict__ Hh, int chunkN, int n0, int swz) {
    int blk = edge_blk_swz(blockIdx.x, swz);
    int node = blk * 4 + (threadIdx.x >> 6);
    if (node >= chunkN) return;
    int lane = threadIdx.x & 63;
    int bc = lane * 8;                 // head = lane/16
    float xrv[8], attv[8];
    {
        ushort8 t0 = *(const ushort8*)&xlr[(size_t)node * 1024 + 512 + bc];
        #pragma unroll
        for (int k = 0; k < 8; ++k) xrv[k] = bf2f(t0[k]);
        float4 a0 = *(const float4*)&att[bc];
        float4 a1 = *(const float4*)&att[bc + 4];
        attv[0]=a0.x; attv[1]=a0.y; attv[2]=a0.z; attv[3]=a0.w;
        attv[4]=a1.x; attv[5]=a1.y; attv[6]=a1.z; attv[7]=a1.w;
    }
    float acc[8] = {0,0,0,0,0,0,0,0};
    float m = -3.0e38f, d = 0.0f;
    int e0 = roff[n0 + node], e1 = roff[n0 + node + 1];
    ushort8 cv;
    {
        int s = csrc[e0] - n0;
        cv = *(const ushort8*)&xlr[(size_t)s * 1024 + bc];
    }
    for (int e = e0; e < e1; ++e) {
        float xv[8];
        #pragma unroll
        for (int k = 0; k < 8; ++k) xv[k] = bf2f(cv[k]);
        if (e + 1 < e1) {              // prefetch next edge
            int s2 = csrc[e + 1] - n0;
            cv = *(const ushort8*)&xlr[(size_t)s2 * 1024 + bc];
        }
        float p = 0.0f;
        #pragma unroll
        for (int k = 0; k < 8; ++k) {
            float t = xv[k] + xrv[k];
            t = (t > 0.0f) ? t : 0.2f * t;
            p = fmaf(t, attv[k], p);
        }
        p += __shfl_xor(p, 1); p += __shfl_xor(p, 2);
        p += __shfl_xor(p, 4); p += __shfl_xor(p, 8);
        float mn = fmaxf(m, p);
        float sc = __expf(m - mn);
        float w  = __expf(p - mn);
        d = d * sc + w;
        #pragma unroll
        for (int k = 0; k < 8; ++k) acc[k] = fmaf(acc[k], sc, w * xv[k]);
        m = mn;
    }
    float inv = 1.0f / (d + 1e-16f);
    ushort8 hv;
    #pragma unroll
    for (int k = 0; k < 8; ++k)
        hv[k] = f2bf_rn(acc[k] * inv + bias[bc + k]);
    *(ushort8*)&Hh[(size_t)node * 512 + bc] = hv;
}

// ------- Layer 2 edge kernel: fused head-mean + feature-mean, xlr bf16 [N][512] --

__global__ __launch_bounds__(256) void gat_edge2(
        const unsigned short* __restrict__ xlr,
        const float* __restrict__ att, const float* __restrict__ bias,
        const int* __restrict__ roff, const int* __restrict__ csrc,
        float* __restrict__ out, int chunkN, int n0, int swz) {
    int blk = edge_blk_swz(blockIdx.x, swz);
    int node = blk * 4 + (threadIdx.x >> 6);
    if (node >= chunkN) return;
    int lane = threadIdx.x & 63;
    int bc = lane * 4;                 // within [0,256); head = lane/16
    float xrv[4], attv[4];
    {
        ushort4v t0 = *(const ushort4v*)&xlr[(size_t)node * 512 + 256 + bc];
        #pragma unroll
        for (int k = 0; k < 4; ++k) xrv[k] = bf2f(t0[k]);
        float4 a0 = *(const float4*)&att[bc];
        attv[0]=a0.x; attv[1]=a0.y; attv[2]=a0.z; attv[3]=a0.w;
    }
    float acc[4] = {0,0,0,0};
    float m = -3.0e38f, d = 0.0f;
    int e0 = roff[n0 + node], e1 = roff[n0 + node + 1];
    ushort4v cv;
    {
        int s = csrc[e0] - n0;
        cv = *(const ushort4v*)&xlr[(size_t)s * 512 + bc];
    }
    for (int e = e0; e < e1; ++e) {
        float xv[4];
        #pragma unroll
        for (int k = 0; k < 4; ++k) xv[k] = bf2f(cv[k]);
        if (e + 1 < e1) {
            int s2 = csrc[e + 1] - n0;
            cv = *(const ushort4v*)&xlr[(size_t)s2 * 512 + bc];
        }
        float p = 0.0f;
        #pragma unroll
        for (int k = 0; k < 4; ++k) {
            float t = xv[k] + xrv[k];
            t = (t > 0.0f) ? t : 0.2f * t;
            p = fmaf(t, attv[k], p);
        }
        p += __shfl_xor(p, 1); p += __shfl_xor(p, 2);
        p += __shfl_xor(p, 4); p += __shfl_xor(p, 8);
        float mn = fmaxf(m, p);
        float sc = __expf(m - mn);
        float w  = __expf(p - mn);
        d = d * sc + w;
        #pragma unroll
        for (int k = 0; k < 4; ++k) acc[k] = fmaf(acc[k], sc, w * xv[k]);
        m = mn;
    }
    float inv = 1.0f / (d + 1e-16f);
    float v[4];
    #pragma unroll
    for (int k = 0; k < 4; ++k) v[k] = acc[k] * inv;
    #pragma unroll
    for (int k = 0; k < 4; ++k) {
        v[k] += __shfl_xor(v[k], 16);
        v[k] += __shfl_xor(v[k], 32);
    }
    int cb = (lane & 15) * 4;
    float s = 0.25f * (v[0] + v[1] + v[2] + v[3])
            + bias[cb] + bias[cb + 1] + bias[cb + 2] + bias[cb + 3];
    s += __shfl_xor(s, 1); s += __shfl_xor(s, 2);
    s += __shfl_xor(s, 4); s += __shfl_xor(s, 8);
    if (lane == 0) out[node] = s * (1.0f / 64.0f);
}

// ---------------- launch ----------------

extern "C" void kernel_launch(void* const* d_in, const int* in_sizes, int n_in,
                              void* d_out, int out_size, void* d_ws, size_t ws_size,
                              hipStream_t stream) {
    const float* x    = (const float*)d_in[0];
    const int*   ei   = (const int*)d_in[1];
    const float* Wl1  = (const float*)d_in[3];
    const float* bl1  = (const float*)d_in[4];
    const float* Wr1  = (const float*)d_in[5];
    const float* br1  = (const float*)d_in[6];
    const float* att1 = (const float*)d_in[7];
    const float* bias1= (const float*)d_in[8];
    const float* Wl2  = (const float*)d_in[9];
    const float* bl2  = (const float*)d_in[10];
    const float* Wr2  = (const float*)d_in[11];
    const float* br2  = (const float*)d_in[12];
    const float* att2 = (const float*)d_in[13];
    const float* bias2= (const float*)d_in[14];
    float* out = (float*)d_out;

    const int F = 512;
    const int N = in_sizes[0] / F;        // 32768
    const int E = in_sizes[1] / 2;        // 262144
    const int NG = 64;
    const int NPG = N / NG;               // 512
    const int EPG = E / NG + NPG;         // 4608

    char* w = (char*)d_ws;
    int* roff = (int*)(w);
    int* cnt  = (int*)(w + 0x40000);
    int* csrc = (int*)(w + 0x80000);
    unsigned short* wc1 = (unsigned short*)(w + 0x200000);   // [1024][512] bf16
    unsigned short* wc2 = (unsigned short*)(w + 0x400000);   // [512][512] bf16
    float* bcat1 = (float*)(w + 0x500000);
    float* bcat2 = (float*)(w + 0x501000);
    const size_t HDR = 6ull << 20;

    int chunkG = NG;
    while (chunkG > 1) {
        size_t need = HDR + 3ull * (size_t)chunkG * NPG * 512 * 4;
        if (need <= ws_size) break;
        chunkG >>= 1;
    }
    const int chunkN = chunkG * NPG;
    const size_t BSZ = (size_t)chunkN * 512 * 4;
    char* R1 = w + HDR;
    char* R2 = w + HDR + BSZ;
    const int swz = (chunkG % 8 == 0) ? 1 : 0;

    hipMemsetAsync(cnt, 0, (size_t)N * 4, stream);
    hist_kernel<<<1024, 256, 0, stream>>>(ei, E, N, cnt);
    scan_pg<<<NG, 512, 0, stream>>>(cnt, roff, NPG, EPG);
    hipMemsetAsync(cnt, 0, (size_t)N * 4, stream);
    scatter_kernel<<<1024, 256, 0, stream>>>(ei, E, N, roff, cnt, csrc);

    tcast_kernel<<<dim3(512/32, 512/32), 256, 0, stream>>>(Wl1, wc1, 512, 512);
    tcast_kernel<<<dim3(512/32, 512/32), 256, 0, stream>>>(Wr1, wc1 + 512*512, 512, 512);
    tcast_kernel<<<dim3(256/32, 512/32), 256, 0, stream>>>(Wl2, wc2, 512, 256);
    tcast_kernel<<<dim3(256/32, 512/32), 256, 0, stream>>>(Wr2, wc2 + 256*512, 512, 256);
    hipMemcpyAsync(bcat1,       bl1, 512 * 4, hipMemcpyDeviceToDevice, stream);
    hipMemcpyAsync(bcat1 + 512, br1, 512 * 4, hipMemcpyDeviceToDevice, stream);
    hipMemcpyAsync(bcat2,       bl2, 256 * 4, hipMemcpyDeviceToDevice, stream);
    hipMemcpyAsync(bcat2 + 256, br2, 256 * 4, hipMemcpyDeviceToDevice, stream);

    for (int g0 = 0; g0 < NG; g0 += chunkG) {
        int n0 = g0 * NPG;
        const float* xc = x + (size_t)n0 * 512;
        unsigned short* Xh   = (unsigned short*)R1;
        unsigned short* xlr1 = (unsigned short*)R2;  // bf16 [chunkN][1024]
        unsigned short* Hh   = (unsigned short*)R1;  // reuse (Xh dead after L1 gemm)
        unsigned short* xlr2 = (unsigned short*)R2;  // bf16 [chunkN][512]

        cast_hi_kernel<<<2048, 256, 0, stream>>>(xc, Xh, chunkN * 512 / 4);
        gemm128b<<<dim3(1024/128, chunkN/128), 256, 0, stream>>>(
            Xh, wc1, bcat1, xlr1, chunkN, 512, 1024);
        gat_edge1<<<(chunkN * 64) / 256, 256, 0, stream>>>(
            xlr1, att1, bias1, roff, csrc, Hh, chunkN, n0, swz);

        gemm128b<<<dim3(512/128, chunkN/128), 256, 0, stream>>>(
            Hh, wc2, bcat2, xlr2, chunkN, 512, 512);
        gat_edge2<<<(chunkN * 64) / 256, 256, 0, stream>>>(
            xlr2, att2, bias2, roff, csrc, out + n0, chunkN, n0, swz);
    }
}

// Round 17
// 206.730 us; speedup vs baseline: 1.2448x; 1.0368x over previous
//
#include <hip/hip_runtime.h>
#include <hip/hip_bf16.h>

// GATv2 2-layer GNN. Round 17 (= round 16 + typedef fix): edge kernels get
// (1) leaky = 0.6t+0.4|t| fused into score fma (abs = free modifier),
// (2) paired bf16->f32 convert (and/lshl), (3) defer-max online softmax
// (THR=8, T13) -> ~32% fewer VALU ops/edge. GEMMs/CSR/casts = round 15.
// N=32768 (64 graphs x 512), F=512, E=262144 (+N self loops), H=4, C1=128, C2=64.

typedef __bf16 bf16_t;
typedef bf16_t bf16x8 __attribute__((ext_vector_type(8)));
typedef float f32x4 __attribute__((ext_vector_type(4)));
typedef unsigned short ushort8 __attribute__((ext_vector_type(8)));

__device__ __forceinline__ unsigned short f2bf_rn(float f) {
    unsigned u = __float_as_uint(f);
    unsigned r = (u + 0x7FFFu + ((u >> 16) & 1u)) >> 16;
    return (unsigned short)r;
}

// ---------------- CSR build ----------------

__global__ void hist_kernel(const int* __restrict__ ei, int E, int N,
                            int* __restrict__ deg) {
    int total = E + N;
    for (int e = blockIdx.x * blockDim.x + threadIdx.x; e < total;
         e += gridDim.x * blockDim.x) {
        int dst = (e < E) ? ei[E + e] : (e - E);
        atomicAdd(&deg[dst], 1);
    }
}

__global__ __launch_bounds__(512) void scan_pg(const int* __restrict__ deg,
                                               int* __restrict__ off,
                                               int NPG, int EPG) {
    __shared__ int buf[512];
    int g = blockIdx.x, tid = threadIdx.x;
    int base = g * NPG;
    buf[tid] = deg[base + tid];
    __syncthreads();
    #pragma unroll
    for (int ofs = 1; ofs < 512; ofs <<= 1) {
        int t = (tid >= ofs) ? buf[tid - ofs] : 0;
        __syncthreads();
        buf[tid] += t;
        __syncthreads();
    }
    off[base + tid + 1] = g * EPG + buf[tid];
    if (tid == 0) off[base] = g * EPG;
}

__global__ void scatter_kernel(const int* __restrict__ ei, int E, int N,
                               const int* __restrict__ off, int* __restrict__ cnt,
                               int* __restrict__ csrc) {
    int total = E + N;
    for (int e = blockIdx.x * blockDim.x + threadIdx.x; e < total;
         e += gridDim.x * blockDim.x) {
        int src, dst;
        if (e < E) { src = ei[e]; dst = ei[E + e]; }
        else       { src = e - E; dst = e - E; }
        int pos = off[dst] + atomicAdd(&cnt[dst], 1);
        csrc[pos] = src;
    }
}

// ---------------- fp32 -> bf16 cast (hi only) ----------------

__global__ __launch_bounds__(256) void cast_hi_kernel(
        const float* __restrict__ X, unsigned short* __restrict__ hi, int n4) {
    for (int i = blockIdx.x * blockDim.x + threadIdx.x; i < n4;
         i += gridDim.x * blockDim.x) {
        float4 v = ((const float4*)X)[i];
        ushort4 h;
        h.x = f2bf_rn(v.x); h.y = f2bf_rn(v.y);
        h.z = f2bf_rn(v.z); h.w = f2bf_rn(v.w);
        ((ushort4*)hi)[i] = h;
    }
}

// W [K][Nc] fp32 -> Wt [Nc][K] bf16 (transpose + round-to-nearest cast)
__global__ __launch_bounds__(256) void tcast_kernel(
        const float* __restrict__ W, unsigned short* __restrict__ th,
        int K, int Nc) {
    __shared__ float t[32][33];
    int bx = blockIdx.x, by = blockIdx.y;
    int lx = threadIdx.x & 31, ly = threadIdx.x >> 5;
    #pragma unroll
    for (int r = ly; r < 32; r += 8)
        t[r][lx] = W[(size_t)(by * 32 + r) * Nc + bx * 32 + lx];
    __syncthreads();
    #pragma unroll
    for (int r = ly; r < 32; r += 8)
        th[(size_t)(bx * 32 + r) * K + by * 32 + lx] = f2bf_rn(t[lx][r]);
}

// ---- 128x128 GEMM, 4 waves, pure bf16, 2-buffer dbuf (32KB -> 5 blk/CU) ----

__global__ __launch_bounds__(256) void gemm128b(
        const unsigned short* __restrict__ A,
        const unsigned short* __restrict__ B,
        const float* __restrict__ bias, unsigned short* __restrict__ C,
        int M, int K, int Nc) {
    constexpr int NQ  = 4;
    constexpr int BUF = 16384;
    __shared__ __align__(16) char smem[2 * BUF];

    int tid  = threadIdx.x;
    int wave = tid >> 6, lane = tid & 63;
    int wr = wave >> 1, wc = wave & 1;

    int bx = blockIdx.x, by = blockIdx.y;
    if ((gridDim.y & 7) == 0) {                 // XCD swizzle
        int d = blockIdx.y * gridDim.x + blockIdx.x;
        int x = d & 7, i = d >> 3;
        by = (i / gridDim.x) * 8 + x;
        bx = i % gridDim.x;
    }
    int m0 = by * 128, n0 = bx * 128;

    const unsigned short* gsrc[NQ];
    int loff[NQ];
    #pragma unroll
    for (int q = 0; q < NQ; ++q) {
        int o    = q * 4096 + tid * 16;
        int tile = o >> 13;
        int ot   = o & 8191;
        int row  = ot >> 6;
        int slot = (ot >> 4) & 3;
        int sl   = slot ^ ((row >> 1) & 3);
        const unsigned short* base =
            (tile == 0) ? (A + (size_t)(m0 + row) * K)
                        : (B + (size_t)(n0 + row) * K);
        gsrc[q] = base + sl * 8;
        loff[q] = q * 4096 + wave * 1024;
    }

    f32x4 acc[4][4];
    #pragma unroll
    for (int i = 0; i < 4; ++i)
        #pragma unroll
        for (int j = 0; j < 4; ++j) acc[i][j] = (f32x4){0.f, 0.f, 0.f, 0.f};

    int r = lane & 15, g = lane >> 4;
    int sw = (g ^ ((r >> 1) & 3)) * 16;

    #pragma unroll
    for (int q = 0; q < NQ; ++q) {
        __builtin_amdgcn_global_load_lds(
            (const __attribute__((address_space(1))) void*)(gsrc[q]),
            (__attribute__((address_space(3))) void*)(smem + loff[q]), 16, 0, 0);
        gsrc[q] += 32;
    }
    __syncthreads();

    const int NT = K >> 5;
    int cur = 0;
    for (int t = 0; t < NT; ++t) {
        if (t + 1 < NT) {
            #pragma unroll
            for (int q = 0; q < NQ; ++q) {
                __builtin_amdgcn_global_load_lds(
                    (const __attribute__((address_space(1))) void*)(gsrc[q]),
                    (__attribute__((address_space(3))) void*)(smem + loff[q] + (cur ^ BUF)),
                    16, 0, 0);
                gsrc[q] += 32;
            }
        }
        const char* sb = smem + cur;
        bf16x8 a[4], b[4];
        #pragma unroll
        for (int i = 0; i < 4; ++i) {
            int offA = (wr * 64 + i * 16 + r) * 64 + sw;
            int offB = (wc * 64 + i * 16 + r) * 64 + sw;
            a[i] = *(const bf16x8*)(sb + offA);
            b[i] = *(const bf16x8*)(sb + 8192 + offB);
        }
        __builtin_amdgcn_s_setprio(1);
        #pragma unroll
        for (int i = 0; i < 4; ++i)
            #pragma unroll
            for (int j = 0; j < 4; ++j)
                acc[i][j] = __builtin_amdgcn_mfma_f32_16x16x32_bf16(a[i], b[j], acc[i][j], 0, 0, 0);
        __builtin_amdgcn_s_setprio(0);
        __syncthreads();
        cur ^= BUF;
    }

    #pragma unroll
    for (int j = 0; j < 4; ++j) {
        int col = n0 + wc * 64 + j * 16 + r;
        float bv = bias[col];
        #pragma unroll
        for (int i = 0; i < 4; ++i) {
            int rowb = m0 + wr * 64 + i * 16 + g * 4;
            #pragma unroll
            for (int t = 0; t < 4; ++t)
                C[(size_t)(rowb + t) * Nc + col] = f2bf_rn(acc[i][j][t] + bv);
        }
    }
}

// -------- XCD swizzle for edge kernels: graph g -> XCD g%8 --------

__device__ __forceinline__ int edge_blk_swz(int blk, int swz) {
    if (swz) {
        int x = blk & 7, i = blk >> 3;
        blk = (i >> 7) * 1024 + x * 128 + (i & 127);
    }
    return blk;
}

// ---------------- Layer 1 edge kernel: wave per node, 8 ch/lane ----------------
// xlr bf16 [chunkN][1024] (xl | xr). Defer-max softmax; leaky folded via abs.

__global__ __launch_bounds__(256) void gat_edge1(
        const unsigned short* __restrict__ xlr,
        const float* __restrict__ att, const float* __restrict__ bias,
        const int* __restrict__ roff, const int* __restrict__ csrc,
        unsigned short* __restrict__ Hh, int chunkN, int n0, int swz) {
    int blk = edge_blk_swz(blockIdx.x, swz);
    int node = blk * 4 + (threadIdx.x >> 6);
    if (node >= chunkN) return;
    int lane = threadIdx.x & 63;
    int bc = lane * 8;                 // head = lane/16
    float xrv[8], att6[8], att4[8];
    {
        uint4 t0 = *(const uint4*)&xlr[(size_t)node * 1024 + 512 + bc];
        const unsigned* u = (const unsigned*)&t0;
        #pragma unroll
        for (int j = 0; j < 4; ++j) {
            xrv[2*j]   = __uint_as_float(u[j] << 16);
            xrv[2*j+1] = __uint_as_float(u[j] & 0xFFFF0000u);
        }
        float4 a0 = *(const float4*)&att[bc];
        float4 a1 = *(const float4*)&att[bc + 4];
        float av[8] = {a0.x, a0.y, a0.z, a0.w, a1.x, a1.y, a1.z, a1.w};
        #pragma unroll
        for (int k = 0; k < 8; ++k) { att6[k] = 0.6f * av[k]; att4[k] = 0.4f * av[k]; }
    }
    float acc[8];
    float m = 0.0f, d = 0.0f;
    int e0 = roff[n0 + node], e1 = roff[n0 + node + 1];
    uint4 cv;
    {
        int s = csrc[e0] - n0;
        cv = *(const uint4*)&xlr[(size_t)s * 1024 + bc];
    }
    for (int e = e0; e < e1; ++e) {
        float xv[8];
        {
            const unsigned* u = (const unsigned*)&cv;
            #pragma unroll
            for (int j = 0; j < 4; ++j) {
                xv[2*j]   = __uint_as_float(u[j] << 16);
                xv[2*j+1] = __uint_as_float(u[j] & 0xFFFF0000u);
            }
        }
        if (e + 1 < e1) {              // prefetch next edge
            int s2 = csrc[e + 1] - n0;
            cv = *(const uint4*)&xlr[(size_t)s2 * 1024 + bc];
        }
        float p = 0.0f;
        #pragma unroll
        for (int k = 0; k < 8; ++k) {
            float t = xv[k] + xrv[k];
            p = fmaf(att6[k], t, p);
            p = fmaf(att4[k], fabsf(t), p);    // leaky = 0.6t + 0.4|t|
        }
        p += __shfl_xor(p, 1); p += __shfl_xor(p, 2);
        p += __shfl_xor(p, 4); p += __shfl_xor(p, 8);
        if (e == e0) {                 // first edge (deg >= 1: self loop)
            m = p; d = 1.0f;
            #pragma unroll
            for (int k = 0; k < 8; ++k) acc[k] = xv[k];
        } else if (p > m + 8.0f) {     // rare: rescale to new reference
            float sc = __expf(m - p);
            d = fmaf(d, sc, 1.0f);
            #pragma unroll
            for (int k = 0; k < 8; ++k) acc[k] = fmaf(acc[k], sc, xv[k]);
            m = p;
        } else {                       // common: no rescale
            float w = __expf(p - m);
            d += w;
            #pragma unroll
            for (int k = 0; k < 8; ++k) acc[k] = fmaf(w, xv[k], acc[k]);
        }
    }
    float inv = 1.0f / d;
    ushort8 hv;
    #pragma unroll
    for (int k = 0; k < 8; ++k)
        ((unsigned short*)&hv)[k] = f2bf_rn(fmaf(acc[k], inv, bias[bc + k]));
    *(ushort8*)&Hh[(size_t)node * 512 + bc] = hv;
}

// ------- Layer 2 edge kernel: fused head-mean + feature-mean, 4 ch/lane -------

__global__ __launch_bounds__(256) void gat_edge2(
        const unsigned short* __restrict__ xlr,
        const float* __restrict__ att, const float* __restrict__ bias,
        const int* __restrict__ roff, const int* __restrict__ csrc,
        float* __restrict__ out, int chunkN, int n0, int swz) {
    int blk = edge_blk_swz(blockIdx.x, swz);
    int node = blk * 4 + (threadIdx.x >> 6);
    if (node >= chunkN) return;
    int lane = threadIdx.x & 63;
    int bc = lane * 4;                 // within [0,256); head = lane/16
    float xrv[4], att6[4], att4[4];
    {
        uint2 t0 = *(const uint2*)&xlr[(size_t)node * 512 + 256 + bc];
        const unsigned* u = (const unsigned*)&t0;
        #pragma unroll
        for (int j = 0; j < 2; ++j) {
            xrv[2*j]   = __uint_as_float(u[j] << 16);
            xrv[2*j+1] = __uint_as_float(u[j] & 0xFFFF0000u);
        }
        float4 a0 = *(const float4*)&att[bc];
        float av[4] = {a0.x, a0.y, a0.z, a0.w};
        #pragma unroll
        for (int k = 0; k < 4; ++k) { att6[k] = 0.6f * av[k]; att4[k] = 0.4f * av[k]; }
    }
    float acc[4];
    float m = 0.0f, d = 0.0f;
    int e0 = roff[n0 + node], e1 = roff[n0 + node + 1];
    uint2 cv;
    {
        int s = csrc[e0] - n0;
        cv = *(const uint2*)&xlr[(size_t)s * 512 + bc];
    }
    for (int e = e0; e < e1; ++e) {
        float xv[4];
        {
            const unsigned* u = (const unsigned*)&cv;
            #pragma unroll
            for (int j = 0; j < 2; ++j) {
                xv[2*j]   = __uint_as_float(u[j] << 16);
                xv[2*j+1] = __uint_as_float(u[j] & 0xFFFF0000u);
            }
        }
        if (e + 1 < e1) {
            int s2 = csrc[e + 1] - n0;
            cv = *(const uint2*)&xlr[(size_t)s2 * 512 + bc];
        }
        float p = 0.0f;
        #pragma unroll
        for (int k = 0; k < 4; ++k) {
            float t = xv[k] + xrv[k];
            p = fmaf(att6[k], t, p);
            p = fmaf(att4[k], fabsf(t), p);
        }
        p += __shfl_xor(p, 1); p += __shfl_xor(p, 2);
        p += __shfl_xor(p, 4); p += __shfl_xor(p, 8);
        if (e == e0) {
            m = p; d = 1.0f;
            #pragma unroll
            for (int k = 0; k < 4; ++k) acc[k] = xv[k];
        } else if (p > m + 8.0f) {
            float sc = __expf(m - p);
            d = fmaf(d, sc, 1.0f);
            #pragma unroll
            for (int k = 0; k < 4; ++k) acc[k] = fmaf(acc[k], sc, xv[k]);
            m = p;
        } else {
            float w = __expf(p - m);
            d += w;
            #pragma unroll
            for (int k = 0; k < 4; ++k) acc[k] = fmaf(w, xv[k], acc[k]);
        }
    }
    float inv = 1.0f / d;
    float v[4];
    #pragma unroll
    for (int k = 0; k < 4; ++k) v[k] = acc[k] * inv;
    #pragma unroll
    for (int k = 0; k < 4; ++k) {
        v[k] += __shfl_xor(v[k], 16);
        v[k] += __shfl_xor(v[k], 32);
    }
    int cb = (lane & 15) * 4;
    float s = 0.25f * (v[0] + v[1] + v[2] + v[3])
            + bias[cb] + bias[cb + 1] + bias[cb + 2] + bias[cb + 3];
    s += __shfl_xor(s, 1); s += __shfl_xor(s, 2);
    s += __shfl_xor(s, 4); s += __shfl_xor(s, 8);
    if (lane == 0) out[node] = s * (1.0f / 64.0f);
}

// ---------------- launch ----------------

extern "C" void kernel_launch(void* const* d_in, const int* in_sizes, int n_in,
                              void* d_out, int out_size, void* d_ws, size_t ws_size,
                              hipStream_t stream) {
    const float* x    = (const float*)d_in[0];
    const int*   ei   = (const int*)d_in[1];
    const float* Wl1  = (const float*)d_in[3];
    const float* bl1  = (const float*)d_in[4];
    const float* Wr1  = (const float*)d_in[5];
    const float* br1  = (const float*)d_in[6];
    const float* att1 = (const float*)d_in[7];
    const float* bias1= (const float*)d_in[8];
    const float* Wl2  = (const float*)d_in[9];
    const float* bl2  = (const float*)d_in[10];
    const float* Wr2  = (const float*)d_in[11];
    const float* br2  = (const float*)d_in[12];
    const float* att2 = (const float*)d_in[13];
    const float* bias2= (const float*)d_in[14];
    float* out = (float*)d_out;

    const int F = 512;
    const int N = in_sizes[0] / F;        // 32768
    const int E = in_sizes[1] / 2;        // 262144
    const int NG = 64;
    const int NPG = N / NG;               // 512
    const int EPG = E / NG + NPG;         // 4608

    char* w = (char*)d_ws;
    int* roff = (int*)(w);
    int* cnt  = (int*)(w + 0x40000);
    int* csrc = (int*)(w + 0x80000);
    unsigned short* wc1 = (unsigned short*)(w + 0x200000);   // [1024][512] bf16
    unsigned short* wc2 = (unsigned short*)(w + 0x400000);   // [512][512] bf16
    float* bcat1 = (float*)(w + 0x500000);
    float* bcat2 = (float*)(w + 0x501000);
    const size_t HDR = 6ull << 20;

    int chunkG = NG;
    while (chunkG > 1) {
        size_t need = HDR + 3ull * (size_t)chunkG * NPG * 512 * 4;
        if (need <= ws_size) break;
        chunkG >>= 1;
    }
    const int chunkN = chunkG * NPG;
    const size_t BSZ = (size_t)chunkN * 512 * 4;
    char* R1 = w + HDR;
    char* R2 = w + HDR + BSZ;
    const int swz = (chunkG % 8 == 0) ? 1 : 0;

    hipMemsetAsync(cnt, 0, (size_t)N * 4, stream);
    hist_kernel<<<1024, 256, 0, stream>>>(ei, E, N, cnt);
    scan_pg<<<NG, 512, 0, stream>>>(cnt, roff, NPG, EPG);
    hipMemsetAsync(cnt, 0, (size_t)N * 4, stream);
    scatter_kernel<<<1024, 256, 0, stream>>>(ei, E, N, roff, cnt, csrc);

    tcast_kernel<<<dim3(512/32, 512/32), 256, 0, stream>>>(Wl1, wc1, 512, 512);
    tcast_kernel<<<dim3(512/32, 512/32), 256, 0, stream>>>(Wr1, wc1 + 512*512, 512, 512);
    tcast_kernel<<<dim3(256/32, 512/32), 256, 0, stream>>>(Wl2, wc2, 512, 256);
    tcast_kernel<<<dim3(256/32, 512/32), 256, 0, stream>>>(Wr2, wc2 + 256*512, 512, 256);
    hipMemcpyAsync(bcat1,       bl1, 512 * 4, hipMemcpyDeviceToDevice, stream);
    hipMemcpyAsync(bcat1 + 512, br1, 512 * 4, hipMemcpyDeviceToDevice, stream);
    hipMemcpyAsync(bcat2,       bl2, 256 * 4, hipMemcpyDeviceToDevice, stream);
    hipMemcpyAsync(bcat2 + 256, br2, 256 * 4, hipMemcpyDeviceToDevice, stream);

    for (int g0 = 0; g0 < NG; g0 += chunkG) {
        int n0 = g0 * NPG;
        const float* xc = x + (size_t)n0 * 512;
        unsigned short* Xh   = (unsigned short*)R1;
        unsigned short* xlr1 = (unsigned short*)R2;  // bf16 [chunkN][1024]
        unsigned short* Hh   = (unsigned short*)R1;  // reuse (Xh dead after L1 gemm)
        unsigned short* xlr2 = (unsigned short*)R2;  // bf16 [chunkN][512]

        cast_hi_kernel<<<2048, 256, 0, stream>>>(xc, Xh, chunkN * 512 / 4);
        gemm128b<<<dim3(1024/128, chunkN/128), 256, 0, stream>>>(
            Xh, wc1, bcat1, xlr1, chunkN, 512, 1024);
        gat_edge1<<<(chunkN * 64) / 256, 256, 0, stream>>>(
            xlr1, att1, bias1, roff, csrc, Hh, chunkN, n0, swz);

        gemm128b<<<dim3(512/128, chunkN/128), 256, 0, stream>>>(
            Hh, wc2, bcat2, xlr2, chunkN, 512, 512);
        gat_edge2<<<(chunkN * 64) / 256, 256, 0, stream>>>(
            xlr2, att2, bias2, roff, csrc, out + n0, chunkN, n0, swz);
    }
}

// Round 18
// 176.727 us; speedup vs baseline: 1.4562x; 1.1698x over previous
//
#include <hip/hip_runtime.h>
#include <hip/hip_bf16.h>

// GATv2 2-layer GNN. Round 18: dispatch-count reduction. Single-kernel
// per-graph CSR build (LDS hist+scan+scatter, 1 block/graph, replaces 6
// dispatches), fused 4x tcast into one kernel, fused bias concat kernel.
// Compute kernels (pure-bf16 128^2 GEMM, defer-max edge kernels) = round 17.
// N=32768 (64 graphs x 512), F=512, E=262144 (+N self loops), H=4, C1=128, C2=64.

typedef __bf16 bf16_t;
typedef bf16_t bf16x8 __attribute__((ext_vector_type(8)));
typedef float f32x4 __attribute__((ext_vector_type(4)));
typedef unsigned short ushort8 __attribute__((ext_vector_type(8)));

__device__ __forceinline__ unsigned short f2bf_rn(float f) {
    unsigned u = __float_as_uint(f);
    unsigned r = (u + 0x7FFFu + ((u >> 16) & 1u)) >> 16;
    return (unsigned short)r;
}

// ------------- CSR build: one block (512 thr) per graph, all in LDS ---------
// Graph g owns nodes [g*512,(g+1)*512) and non-loop edges [g*4096,(g+1)*4096).
// Self loop seeded at slot 0 of each node's list (deg init = 1).

__global__ __launch_bounds__(512) void csr_build(
        const int* __restrict__ ei, int E, int NPG, int EPG_NL,
        int* __restrict__ roff, int* __restrict__ csrc) {
    __shared__ int deg[512], buf[512], soff[512], cnt[512];
    int g = blockIdx.x, tid = threadIdx.x;
    int nb = g * NPG;                  // node base
    int eb = g * EPG_NL;               // non-loop edge base
    const int EPG = EPG_NL + NPG;      // 4608 incl self loops
    deg[tid] = 1;                      // self loop
    __syncthreads();
    for (int i = tid; i < EPG_NL; i += 512)
        atomicAdd(&deg[ei[E + eb + i] - nb], 1);
    __syncthreads();
    buf[tid] = deg[tid];
    __syncthreads();
    #pragma unroll
    for (int ofs = 1; ofs < 512; ofs <<= 1) {
        int t = (tid >= ofs) ? buf[tid - ofs] : 0;
        __syncthreads();
        buf[tid] += t;
        __syncthreads();
    }
    int oe = buf[tid] - deg[tid];      // exclusive scan
    soff[tid] = oe;
    roff[nb + tid] = g * EPG + oe;
    if (tid == 511) roff[nb + 512] = g * EPG + buf[511];   // = (g+1)*EPG
    cnt[tid] = 1;
    csrc[g * EPG + oe] = nb + tid;     // self loop at slot 0
    __syncthreads();
    for (int i = tid; i < EPG_NL; i += 512) {
        int dl = ei[E + eb + i] - nb;
        int s  = ei[eb + i];
        int pos = atomicAdd(&cnt[dl], 1);
        csrc[g * EPG + soff[dl] + pos] = s;
    }
}

// ---------------- fp32 -> bf16 cast (hi only) ----------------

__global__ __launch_bounds__(256) void cast_hi_kernel(
        const float* __restrict__ X, unsigned short* __restrict__ hi, int n4) {
    for (int i = blockIdx.x * blockDim.x + threadIdx.x; i < n4;
         i += gridDim.x * blockDim.x) {
        float4 v = ((const float4*)X)[i];
        ushort4 h;
        h.x = f2bf_rn(v.x); h.y = f2bf_rn(v.y);
        h.z = f2bf_rn(v.z); h.w = f2bf_rn(v.w);
        ((ushort4*)hi)[i] = h;
    }
}

// All 4 weights: W [K][Nc] fp32 -> Wt [Nc][K] bf16 (transpose+cast), one launch.
__global__ __launch_bounds__(256) void tcast4_kernel(
        const float* __restrict__ Wl1, const float* __restrict__ Wr1,
        const float* __restrict__ Wl2, const float* __restrict__ Wr2,
        unsigned short* __restrict__ wc1, unsigned short* __restrict__ wc2) {
    int z = blockIdx.z;
    int Nc = (z < 2) ? 512 : 256;
    if (blockIdx.x * 32 >= Nc) return;
    const float* W = (z == 0) ? Wl1 : (z == 1) ? Wr1 : (z == 2) ? Wl2 : Wr2;
    unsigned short* th = (z == 0) ? wc1 : (z == 1) ? wc1 + 512 * 512
                       : (z == 2) ? wc2 : wc2 + 256 * 512;
    const int K = 512;
    __shared__ float t[32][33];
    int bx = blockIdx.x, by = blockIdx.y;
    int lx = threadIdx.x & 31, ly = threadIdx.x >> 5;
    #pragma unroll
    for (int r = ly; r < 32; r += 8)
        t[r][lx] = W[(size_t)(by * 32 + r) * Nc + bx * 32 + lx];
    __syncthreads();
    #pragma unroll
    for (int r = ly; r < 32; r += 8)
        th[(size_t)(bx * 32 + r) * K + by * 32 + lx] = f2bf_rn(t[lx][r]);
}

// bias concat: bcat1 = [bl1|br1] (1024), bcat2 = [bl2|br2] (512)
__global__ __launch_bounds__(512) void bconcat_kernel(
        const float* __restrict__ bl1, const float* __restrict__ br1,
        const float* __restrict__ bl2, const float* __restrict__ br2,
        float* __restrict__ bcat1, float* __restrict__ bcat2) {
    int i = blockIdx.x * 512 + threadIdx.x;
    if (i < 512)        bcat1[i] = bl1[i];
    else if (i < 1024)  bcat1[i] = br1[i - 512];
    else if (i < 1280)  bcat2[i - 1024] = bl2[i - 1024];
    else if (i < 1536)  bcat2[i - 1024] = br2[i - 1280];
}

// ---- 128x128 GEMM, 4 waves, pure bf16, 2-buffer dbuf (32KB -> 5 blk/CU) ----

__global__ __launch_bounds__(256) void gemm128b(
        const unsigned short* __restrict__ A,
        const unsigned short* __restrict__ B,
        const float* __restrict__ bias, unsigned short* __restrict__ C,
        int M, int K, int Nc) {
    constexpr int NQ  = 4;
    constexpr int BUF = 16384;
    __shared__ __align__(16) char smem[2 * BUF];

    int tid  = threadIdx.x;
    int wave = tid >> 6, lane = tid & 63;
    int wr = wave >> 1, wc = wave & 1;

    int bx = blockIdx.x, by = blockIdx.y;
    if ((gridDim.y & 7) == 0) {                 // XCD swizzle
        int d = blockIdx.y * gridDim.x + blockIdx.x;
        int x = d & 7, i = d >> 3;
        by = (i / gridDim.x) * 8 + x;
        bx = i % gridDim.x;
    }
    int m0 = by * 128, n0 = bx * 128;

    const unsigned short* gsrc[NQ];
    int loff[NQ];
    #pragma unroll
    for (int q = 0; q < NQ; ++q) {
        int o    = q * 4096 + tid * 16;
        int tile = o >> 13;
        int ot   = o & 8191;
        int row  = ot >> 6;
        int slot = (ot >> 4) & 3;
        int sl   = slot ^ ((row >> 1) & 3);
        const unsigned short* base =
            (tile == 0) ? (A + (size_t)(m0 + row) * K)
                        : (B + (size_t)(n0 + row) * K);
        gsrc[q] = base + sl * 8;
        loff[q] = q * 4096 + wave * 1024;
    }

    f32x4 acc[4][4];
    #pragma unroll
    for (int i = 0; i < 4; ++i)
        #pragma unroll
        for (int j = 0; j < 4; ++j) acc[i][j] = (f32x4){0.f, 0.f, 0.f, 0.f};

    int r = lane & 15, g = lane >> 4;
    int sw = (g ^ ((r >> 1) & 3)) * 16;

    #pragma unroll
    for (int q = 0; q < NQ; ++q) {
        __builtin_amdgcn_global_load_lds(
            (const __attribute__((address_space(1))) void*)(gsrc[q]),
            (__attribute__((address_space(3))) void*)(smem + loff[q]), 16, 0, 0);
        gsrc[q] += 32;
    }
    __syncthreads();

    const int NT = K >> 5;
    int cur = 0;
    for (int t = 0; t < NT; ++t) {
        if (t + 1 < NT) {
            #pragma unroll
            for (int q = 0; q < NQ; ++q) {
                __builtin_amdgcn_global_load_lds(
                    (const __attribute__((address_space(1))) void*)(gsrc[q]),
                    (__attribute__((address_space(3))) void*)(smem + loff[q] + (cur ^ BUF)),
                    16, 0, 0);
                gsrc[q] += 32;
            }
        }
        const char* sb = smem + cur;
        bf16x8 a[4], b[4];
        #pragma unroll
        for (int i = 0; i < 4; ++i) {
            int offA = (wr * 64 + i * 16 + r) * 64 + sw;
            int offB = (wc * 64 + i * 16 + r) * 64 + sw;
            a[i] = *(const bf16x8*)(sb + offA);
            b[i] = *(const bf16x8*)(sb + 8192 + offB);
        }
        __builtin_amdgcn_s_setprio(1);
        #pragma unroll
        for (int i = 0; i < 4; ++i)
            #pragma unroll
            for (int j = 0; j < 4; ++j)
                acc[i][j] = __builtin_amdgcn_mfma_f32_16x16x32_bf16(a[i], b[j], acc[i][j], 0, 0, 0);
        __builtin_amdgcn_s_setprio(0);
        __syncthreads();
        cur ^= BUF;
    }

    #pragma unroll
    for (int j = 0; j < 4; ++j) {
        int col = n0 + wc * 64 + j * 16 + r;
        float bv = bias[col];
        #pragma unroll
        for (int i = 0; i < 4; ++i) {
            int rowb = m0 + wr * 64 + i * 16 + g * 4;
            #pragma unroll
            for (int t = 0; t < 4; ++t)
                C[(size_t)(rowb + t) * Nc + col] = f2bf_rn(acc[i][j][t] + bv);
        }
    }
}

// -------- XCD swizzle for edge kernels: graph g -> XCD g%8 --------

__device__ __forceinline__ int edge_blk_swz(int blk, int swz) {
    if (swz) {
        int x = blk & 7, i = blk >> 3;
        blk = (i >> 7) * 1024 + x * 128 + (i & 127);
    }
    return blk;
}

// ---------------- Layer 1 edge kernel: wave per node, 8 ch/lane ----------------

__global__ __launch_bounds__(256) void gat_edge1(
        const unsigned short* __restrict__ xlr,
        const float* __restrict__ att, const float* __restrict__ bias,
        const int* __restrict__ roff, const int* __restrict__ csrc,
        unsigned short* __restrict__ Hh, int chunkN, int n0, int swz) {
    int blk = edge_blk_swz(blockIdx.x, swz);
    int node = blk * 4 + (threadIdx.x >> 6);
    if (node >= chunkN) return;
    int lane = threadIdx.x & 63;
    int bc = lane * 8;                 // head = lane/16
    float xrv[8], att6[8], att4[8];
    {
        uint4 t0 = *(const uint4*)&xlr[(size_t)node * 1024 + 512 + bc];
        const unsigned* u = (const unsigned*)&t0;
        #pragma unroll
        for (int j = 0; j < 4; ++j) {
            xrv[2*j]   = __uint_as_float(u[j] << 16);
            xrv[2*j+1] = __uint_as_float(u[j] & 0xFFFF0000u);
        }
        float4 a0 = *(const float4*)&att[bc];
        float4 a1 = *(const float4*)&att[bc + 4];
        float av[8] = {a0.x, a0.y, a0.z, a0.w, a1.x, a1.y, a1.z, a1.w};
        #pragma unroll
        for (int k = 0; k < 8; ++k) { att6[k] = 0.6f * av[k]; att4[k] = 0.4f * av[k]; }
    }
    float acc[8];
    float m = 0.0f, d = 0.0f;
    int e0 = roff[n0 + node], e1 = roff[n0 + node + 1];
    uint4 cv;
    {
        int s = csrc[e0] - n0;
        cv = *(const uint4*)&xlr[(size_t)s * 1024 + bc];
    }
    for (int e = e0; e < e1; ++e) {
        float xv[8];
        {
            const unsigned* u = (const unsigned*)&cv;
            #pragma unroll
            for (int j = 0; j < 4; ++j) {
                xv[2*j]   = __uint_as_float(u[j] << 16);
                xv[2*j+1] = __uint_as_float(u[j] & 0xFFFF0000u);
            }
        }
        if (e + 1 < e1) {              // prefetch next edge
            int s2 = csrc[e + 1] - n0;
            cv = *(const uint4*)&xlr[(size_t)s2 * 1024 + bc];
        }
        float p = 0.0f;
        #pragma unroll
        for (int k = 0; k < 8; ++k) {
            float t = xv[k] + xrv[k];
            p = fmaf(att6[k], t, p);
            p = fmaf(att4[k], fabsf(t), p);    // leaky = 0.6t + 0.4|t|
        }
        p += __shfl_xor(p, 1); p += __shfl_xor(p, 2);
        p += __shfl_xor(p, 4); p += __shfl_xor(p, 8);
        if (e == e0) {                 // first edge (deg >= 1: self loop)
            m = p; d = 1.0f;
            #pragma unroll
            for (int k = 0; k < 8; ++k) acc[k] = xv[k];
        } else if (p > m + 8.0f) {     // rare: rescale to new reference
            float sc = __expf(m - p);
            d = fmaf(d, sc, 1.0f);
            #pragma unroll
            for (int k = 0; k < 8; ++k) acc[k] = fmaf(acc[k], sc, xv[k]);
            m = p;
        } else {                       // common: no rescale
            float w = __expf(p - m);
            d += w;
            #pragma unroll
            for (int k = 0; k < 8; ++k) acc[k] = fmaf(w, xv[k], acc[k]);
        }
    }
    float inv = 1.0f / d;
    ushort8 hv;
    #pragma unroll
    for (int k = 0; k < 8; ++k)
        ((unsigned short*)&hv)[k] = f2bf_rn(fmaf(acc[k], inv, bias[bc + k]));
    *(ushort8*)&Hh[(size_t)node * 512 + bc] = hv;
}

// ------- Layer 2 edge kernel: fused head-mean + feature-mean, 4 ch/lane -------

__global__ __launch_bounds__(256) void gat_edge2(
        const unsigned short* __restrict__ xlr,
        const float* __restrict__ att, const float* __restrict__ bias,
        const int* __restrict__ roff, const int* __restrict__ csrc,
        float* __restrict__ out, int chunkN, int n0, int swz) {
    int blk = edge_blk_swz(blockIdx.x, swz);
    int node = blk * 4 + (threadIdx.x >> 6);
    if (node >= chunkN) return;
    int lane = threadIdx.x & 63;
    int bc = lane * 4;                 // within [0,256); head = lane/16
    float xrv[4], att6[4], att4[4];
    {
        uint2 t0 = *(const uint2*)&xlr[(size_t)node * 512 + 256 + bc];
        const unsigned* u = (const unsigned*)&t0;
        #pragma unroll
        for (int j = 0; j < 2; ++j) {
            xrv[2*j]   = __uint_as_float(u[j] << 16);
            xrv[2*j+1] = __uint_as_float(u[j] & 0xFFFF0000u);
        }
        float4 a0 = *(const float4*)&att[bc];
        float av[4] = {a0.x, a0.y, a0.z, a0.w};
        #pragma unroll
        for (int k = 0; k < 4; ++k) { att6[k] = 0.6f * av[k]; att4[k] = 0.4f * av[k]; }
    }
    float acc[4];
    float m = 0.0f, d = 0.0f;
    int e0 = roff[n0 + node], e1 = roff[n0 + node + 1];
    uint2 cv;
    {
        int s = csrc[e0] - n0;
        cv = *(const uint2*)&xlr[(size_t)s * 512 + bc];
    }
    for (int e = e0; e < e1; ++e) {
        float xv[4];
        {
            const unsigned* u = (const unsigned*)&cv;
            #pragma unroll
            for (int j = 0; j < 2; ++j) {
                xv[2*j]   = __uint_as_float(u[j] << 16);
                xv[2*j+1] = __uint_as_float(u[j] & 0xFFFF0000u);
            }
        }
        if (e + 1 < e1) {
            int s2 = csrc[e + 1] - n0;
            cv = *(const uint2*)&xlr[(size_t)s2 * 512 + bc];
        }
        float p = 0.0f;
        #pragma unroll
        for (int k = 0; k < 4; ++k) {
            float t = xv[k] + xrv[k];
            p = fmaf(att6[k], t, p);
            p = fmaf(att4[k], fabsf(t), p);
        }
        p += __shfl_xor(p, 1); p += __shfl_xor(p, 2);
        p += __shfl_xor(p, 4); p += __shfl_xor(p, 8);
        if (e == e0) {
            m = p; d = 1.0f;
            #pragma unroll
            for (int k = 0; k < 4; ++k) acc[k] = xv[k];
        } else if (p > m + 8.0f) {
            float sc = __expf(m - p);
            d = fmaf(d, sc, 1.0f);
            #pragma unroll
            for (int k = 0; k < 4; ++k) acc[k] = fmaf(acc[k], sc, xv[k]);
            m = p;
        } else {
            float w = __expf(p - m);
            d += w;
            #pragma unroll
            for (int k = 0; k < 4; ++k) acc[k] = fmaf(w, xv[k], acc[k]);
        }
    }
    float inv = 1.0f / d;
    float v[4];
    #pragma unroll
    for (int k = 0; k < 4; ++k) v[k] = acc[k] * inv;
    #pragma unroll
    for (int k = 0; k < 4; ++k) {
        v[k] += __shfl_xor(v[k], 16);
        v[k] += __shfl_xor(v[k], 32);
    }
    int cb = (lane & 15) * 4;
    float s = 0.25f * (v[0] + v[1] + v[2] + v[3])
            + bias[cb] + bias[cb + 1] + bias[cb + 2] + bias[cb + 3];
    s += __shfl_xor(s, 1); s += __shfl_xor(s, 2);
    s += __shfl_xor(s, 4); s += __shfl_xor(s, 8);
    if (lane == 0) out[node] = s * (1.0f / 64.0f);
}

// ---------------- launch ----------------

extern "C" void kernel_launch(void* const* d_in, const int* in_sizes, int n_in,
                              void* d_out, int out_size, void* d_ws, size_t ws_size,
                              hipStream_t stream) {
    const float* x    = (const float*)d_in[0];
    const int*   ei   = (const int*)d_in[1];
    const float* Wl1  = (const float*)d_in[3];
    const float* bl1  = (const float*)d_in[4];
    const float* Wr1  = (const float*)d_in[5];
    const float* br1  = (const float*)d_in[6];
    const float* att1 = (const float*)d_in[7];
    const float* bias1= (const float*)d_in[8];
    const float* Wl2  = (const float*)d_in[9];
    const float* bl2  = (const float*)d_in[10];
    const float* Wr2  = (const float*)d_in[11];
    const float* br2  = (const float*)d_in[12];
    const float* att2 = (const float*)d_in[13];
    const float* bias2= (const float*)d_in[14];
    float* out = (float*)d_out;

    const int F = 512;
    const int N = in_sizes[0] / F;        // 32768
    const int E = in_sizes[1] / 2;        // 262144
    const int NG = 64;
    const int NPG = N / NG;               // 512
    const int EPG_NL = E / NG;            // 4096 non-loop edges per graph

    char* w = (char*)d_ws;
    int* roff = (int*)(w);                                   // N+1
    int* csrc = (int*)(w + 0x80000);                         // E+N
    unsigned short* wc1 = (unsigned short*)(w + 0x200000);   // [1024][512] bf16
    unsigned short* wc2 = (unsigned short*)(w + 0x400000);   // [512][512] bf16
    float* bcat1 = (float*)(w + 0x500000);
    float* bcat2 = (float*)(w + 0x501000);
    const size_t HDR = 6ull << 20;

    int chunkG = NG;
    while (chunkG > 1) {
        size_t need = HDR + 3ull * (size_t)chunkG * NPG * 512 * 4;
        if (need <= ws_size) break;
        chunkG >>= 1;
    }
    const int chunkN = chunkG * NPG;
    const size_t BSZ = (size_t)chunkN * 512 * 4;
    char* R1 = w + HDR;
    char* R2 = w + HDR + BSZ;
    const int swz = (chunkG % 8 == 0) ? 1 : 0;

    csr_build<<<NG, 512, 0, stream>>>(ei, E, NPG, EPG_NL, roff, csrc);
    tcast4_kernel<<<dim3(16, 16, 4), 256, 0, stream>>>(Wl1, Wr1, Wl2, Wr2, wc1, wc2);
    bconcat_kernel<<<3, 512, 0, stream>>>(bl1, br1, bl2, br2, bcat1, bcat2);

    for (int g0 = 0; g0 < NG; g0 += chunkG) {
        int n0 = g0 * NPG;
        const float* xc = x + (size_t)n0 * 512;
        unsigned short* Xh   = (unsigned short*)R1;
        unsigned short* xlr1 = (unsigned short*)R2;  // bf16 [chunkN][1024]
        unsigned short* Hh   = (unsigned short*)R1;  // reuse (Xh dead after L1 gemm)
        unsigned short* xlr2 = (unsigned short*)R2;  // bf16 [chunkN][512]

        cast_hi_kernel<<<2048, 256, 0, stream>>>(xc, Xh, chunkN * 512 / 4);
        gemm128b<<<dim3(1024/128, chunkN/128), 256, 0, stream>>>(
            Xh, wc1, bcat1, xlr1, chunkN, 512, 1024);
        gat_edge1<<<(chunkN * 64) / 256, 256, 0, stream>>>(
            xlr1, att1, bias1, roff, csrc, Hh, chunkN, n0, swz);

        gemm128b<<<dim3(512/128, chunkN/128), 256, 0, stream>>>(
            Hh, wc2, bcat2, xlr2, chunkN, 512, 512);
        gat_edge2<<<(chunkN * 64) / 256, 256, 0, stream>>>(
            xlr2, att2, bias2, roff, csrc, out + n0, chunkN, n0, swz);
    }
}

// Round 19
// 173.644 us; speedup vs baseline: 1.4820x; 1.0178x over previous
//
#include <hip/hip_runtime.h>
#include <hip/hip_bf16.h>

// GATv2 2-layer GNN. Round 19: fuse the x fp32->bf16 cast into the L1 GEMM
// (A reg-staged: global fp32 -> regs -> pack -> swizzled ds_write; B stays
// global_load_lds). Removes the 96MB cast pass. L2 GEMM/edge/CSR = round 18.
// N=32768 (64 graphs x 512), F=512, E=262144 (+N self loops), H=4, C1=128, C2=64.

typedef __bf16 bf16_t;
typedef bf16_t bf16x8 __attribute__((ext_vector_type(8)));
typedef float f32x4 __attribute__((ext_vector_type(4)));
typedef unsigned short ushort8 __attribute__((ext_vector_type(8)));

__device__ __forceinline__ unsigned short f2bf_rn(float f) {
    unsigned u = __float_as_uint(f);
    unsigned r = (u + 0x7FFFu + ((u >> 16) & 1u)) >> 16;
    return (unsigned short)r;
}

// ------------- CSR build: one block (512 thr) per graph, all in LDS ---------

__global__ __launch_bounds__(512) void csr_build(
        const int* __restrict__ ei, int E, int NPG, int EPG_NL,
        int* __restrict__ roff, int* __restrict__ csrc) {
    __shared__ int deg[512], buf[512], soff[512], cnt[512];
    int g = blockIdx.x, tid = threadIdx.x;
    int nb = g * NPG;
    int eb = g * EPG_NL;
    const int EPG = EPG_NL + NPG;
    deg[tid] = 1;                      // self loop
    __syncthreads();
    for (int i = tid; i < EPG_NL; i += 512)
        atomicAdd(&deg[ei[E + eb + i] - nb], 1);
    __syncthreads();
    buf[tid] = deg[tid];
    __syncthreads();
    #pragma unroll
    for (int ofs = 1; ofs < 512; ofs <<= 1) {
        int t = (tid >= ofs) ? buf[tid - ofs] : 0;
        __syncthreads();
        buf[tid] += t;
        __syncthreads();
    }
    int oe = buf[tid] - deg[tid];
    soff[tid] = oe;
    roff[nb + tid] = g * EPG + oe;
    if (tid == 511) roff[nb + 512] = g * EPG + buf[511];
    cnt[tid] = 1;
    csrc[g * EPG + oe] = nb + tid;
    __syncthreads();
    for (int i = tid; i < EPG_NL; i += 512) {
        int dl = ei[E + eb + i] - nb;
        int s  = ei[eb + i];
        int pos = atomicAdd(&cnt[dl], 1);
        csrc[g * EPG + soff[dl] + pos] = s;
    }
}

// All 4 weights: W [K][Nc] fp32 -> Wt [Nc][K] bf16 (transpose+cast), one launch.
__global__ __launch_bounds__(256) void tcast4_kernel(
        const float* __restrict__ Wl1, const float* __restrict__ Wr1,
        const float* __restrict__ Wl2, const float* __restrict__ Wr2,
        unsigned short* __restrict__ wc1, unsigned short* __restrict__ wc2) {
    int z = blockIdx.z;
    int Nc = (z < 2) ? 512 : 256;
    if (blockIdx.x * 32 >= Nc) return;
    const float* W = (z == 0) ? Wl1 : (z == 1) ? Wr1 : (z == 2) ? Wl2 : Wr2;
    unsigned short* th = (z == 0) ? wc1 : (z == 1) ? wc1 + 512 * 512
                       : (z == 2) ? wc2 : wc2 + 256 * 512;
    const int K = 512;
    __shared__ float t[32][33];
    int bx = blockIdx.x, by = blockIdx.y;
    int lx = threadIdx.x & 31, ly = threadIdx.x >> 5;
    #pragma unroll
    for (int r = ly; r < 32; r += 8)
        t[r][lx] = W[(size_t)(by * 32 + r) * Nc + bx * 32 + lx];
    __syncthreads();
    #pragma unroll
    for (int r = ly; r < 32; r += 8)
        th[(size_t)(bx * 32 + r) * K + by * 32 + lx] = f2bf_rn(t[lx][r]);
}

// bias concat: bcat1 = [bl1|br1] (1024), bcat2 = [bl2|br2] (512)
__global__ __launch_bounds__(512) void bconcat_kernel(
        const float* __restrict__ bl1, const float* __restrict__ br1,
        const float* __restrict__ bl2, const float* __restrict__ br2,
        float* __restrict__ bcat1, float* __restrict__ bcat2) {
    int i = blockIdx.x * 512 + threadIdx.x;
    if (i < 512)        bcat1[i] = bl1[i];
    else if (i < 1024)  bcat1[i] = br1[i - 512];
    else if (i < 1280)  bcat2[i - 1024] = bl2[i - 1024];
    else if (i < 1536)  bcat2[i - 1024] = br2[i - 1280];
}

// ---- L1 GEMM: 128x128, 4 waves, A = fp32 reg-staged + packed to bf16 LDS ----
// C(bf16) = bf16(A_fp32)@B^T + bias. B bf16 [Nc][K] via global_load_lds.
// Same slot involution ((row>>1)&3) applied on ds_write (A) / DMA source (B) /
// ds_read (both). 2-buffer, issue-early staging.

__global__ __launch_bounds__(256) void gemm128f(
        const float* __restrict__ A,
        const unsigned short* __restrict__ B,
        const float* __restrict__ bias, unsigned short* __restrict__ C,
        int M, int K, int Nc) {
    constexpr int BUF = 16384;                  // A(8KB) | B(8KB)
    __shared__ __align__(16) char smem[2 * BUF];

    int tid  = threadIdx.x;
    int wave = tid >> 6, lane = tid & 63;
    int wr = wave >> 1, wc = wave & 1;

    int bx = blockIdx.x, by = blockIdx.y;
    if ((gridDim.y & 7) == 0) {                 // XCD swizzle
        int d = blockIdx.y * gridDim.x + blockIdx.x;
        int x = d & 7, i = d >> 3;
        by = (i / gridDim.x) * 8 + x;
        bx = i % gridDim.x;
    }
    int m0 = by * 128, n0 = bx * 128;

    // B DMA staging (2 loads cover the 8KB B tile)
    const unsigned short* gsrcB[2];
    int loffB[2];
    #pragma unroll
    for (int q = 0; q < 2; ++q) {
        int o    = q * 4096 + tid * 16;
        int row  = o >> 6;
        int slot = (o >> 4) & 3;
        int sl   = slot ^ ((row >> 1) & 3);
        gsrcB[q] = B + (size_t)(n0 + row) * K + sl * 8;
        loffB[q] = 8192 + q * 4096 + wave * 1024;
    }
    // A reg staging: thread covers row=tid>>1, K-half ah=tid&1 (16 fp32)
    int arow = tid >> 1, ah = tid & 1;
    const float* asrc = A + (size_t)(m0 + arow) * K + ah * 16;
    int awoff[2];
    #pragma unroll
    for (int j = 0; j < 2; ++j) {
        int sl = (2 * ah + j) ^ ((arow >> 1) & 3);
        awoff[j] = arow * 64 + sl * 16;
    }

    f32x4 acc[4][4];
    #pragma unroll
    for (int i = 0; i < 4; ++i)
        #pragma unroll
        for (int j = 0; j < 4; ++j) acc[i][j] = (f32x4){0.f, 0.f, 0.f, 0.f};

    int r = lane & 15, g = lane >> 4;
    int sw = (g ^ ((r >> 1) & 3)) * 16;

    // prologue: stage tile 0
    float4 areg[4];
    #pragma unroll
    for (int j = 0; j < 4; ++j) areg[j] = *(const float4*)(asrc + j * 4);
    asrc += 32;
    #pragma unroll
    for (int q = 0; q < 2; ++q) {
        __builtin_amdgcn_global_load_lds(
            (const __attribute__((address_space(1))) void*)(gsrcB[q]),
            (__attribute__((address_space(3))) void*)(smem + loffB[q]), 16, 0, 0);
        gsrcB[q] += 32;
    }
    {
        ushort8 w0, w1;
        const float* af = (const float*)areg;
        #pragma unroll
        for (int k = 0; k < 8; ++k) {
            ((unsigned short*)&w0)[k] = f2bf_rn(af[k]);
            ((unsigned short*)&w1)[k] = f2bf_rn(af[8 + k]);
        }
        *(ushort8*)(smem + awoff[0]) = w0;
        *(ushort8*)(smem + awoff[1]) = w1;
    }
    __syncthreads();

    const int NT = K >> 5;
    int cur = 0;
    for (int t = 0; t < NT; ++t) {
        bool pre = (t + 1 < NT);
        if (pre) {                              // issue next tile's loads EARLY
            #pragma unroll
            for (int j = 0; j < 4; ++j) areg[j] = *(const float4*)(asrc + j * 4);
            asrc += 32;
            #pragma unroll
            for (int q = 0; q < 2; ++q) {
                __builtin_amdgcn_global_load_lds(
                    (const __attribute__((address_space(1))) void*)(gsrcB[q]),
                    (__attribute__((address_space(3))) void*)(smem + loffB[q] + (cur ^ BUF)),
                    16, 0, 0);
                gsrcB[q] += 32;
            }
        }
        const char* sb = smem + cur;
        bf16x8 a[4], b[4];
        #pragma unroll
        for (int i = 0; i < 4; ++i) {
            int offA = (wr * 64 + i * 16 + r) * 64 + sw;
            int offB = (wc * 64 + i * 16 + r) * 64 + sw;
            a[i] = *(const bf16x8*)(sb + offA);
            b[i] = *(const bf16x8*)(sb + 8192 + offB);
        }
        __builtin_amdgcn_s_setprio(1);
        #pragma unroll
        for (int i = 0; i < 4; ++i)
            #pragma unroll
            for (int j = 0; j < 4; ++j)
                acc[i][j] = __builtin_amdgcn_mfma_f32_16x16x32_bf16(a[i], b[j], acc[i][j], 0, 0, 0);
        __builtin_amdgcn_s_setprio(0);
        if (pre) {                              // pack + write A(t+1) late
            ushort8 w0, w1;
            const float* af = (const float*)areg;
            #pragma unroll
            for (int k = 0; k < 8; ++k) {
                ((unsigned short*)&w0)[k] = f2bf_rn(af[k]);
                ((unsigned short*)&w1)[k] = f2bf_rn(af[8 + k]);
            }
            *(ushort8*)(smem + (cur ^ BUF) + awoff[0]) = w0;
            *(ushort8*)(smem + (cur ^ BUF) + awoff[1]) = w1;
        }
        __syncthreads();
        cur ^= BUF;
    }

    #pragma unroll
    for (int j = 0; j < 4; ++j) {
        int col = n0 + wc * 64 + j * 16 + r;
        float bv = bias[col];
        #pragma unroll
        for (int i = 0; i < 4; ++i) {
            int rowb = m0 + wr * 64 + i * 16 + g * 4;
            #pragma unroll
            for (int t = 0; t < 4; ++t)
                C[(size_t)(rowb + t) * Nc + col] = f2bf_rn(acc[i][j][t] + bv);
        }
    }
}

// ---- L2 GEMM: 128x128, 4 waves, pure bf16 A/B via DMA (round-18 kernel) ----

__global__ __launch_bounds__(256) void gemm128b(
        const unsigned short* __restrict__ A,
        const unsigned short* __restrict__ B,
        const float* __restrict__ bias, unsigned short* __restrict__ C,
        int M, int K, int Nc) {
    constexpr int NQ  = 4;
    constexpr int BUF = 16384;
    __shared__ __align__(16) char smem[2 * BUF];

    int tid  = threadIdx.x;
    int wave = tid >> 6, lane = tid & 63;
    int wr = wave >> 1, wc = wave & 1;

    int bx = blockIdx.x, by = blockIdx.y;
    if ((gridDim.y & 7) == 0) {
        int d = blockIdx.y * gridDim.x + blockIdx.x;
        int x = d & 7, i = d >> 3;
        by = (i / gridDim.x) * 8 + x;
        bx = i % gridDim.x;
    }
    int m0 = by * 128, n0 = bx * 128;

    const unsigned short* gsrc[NQ];
    int loff[NQ];
    #pragma unroll
    for (int q = 0; q < NQ; ++q) {
        int o    = q * 4096 + tid * 16;
        int tile = o >> 13;
        int ot   = o & 8191;
        int row  = ot >> 6;
        int slot = (ot >> 4) & 3;
        int sl   = slot ^ ((row >> 1) & 3);
        const unsigned short* base =
            (tile == 0) ? (A + (size_t)(m0 + row) * K)
                        : (B + (size_t)(n0 + row) * K);
        gsrc[q] = base + sl * 8;
        loff[q] = q * 4096 + wave * 1024;
    }

    f32x4 acc[4][4];
    #pragma unroll
    for (int i = 0; i < 4; ++i)
        #pragma unroll
        for (int j = 0; j < 4; ++j) acc[i][j] = (f32x4){0.f, 0.f, 0.f, 0.f};

    int r = lane & 15, g = lane >> 4;
    int sw = (g ^ ((r >> 1) & 3)) * 16;

    #pragma unroll
    for (int q = 0; q < NQ; ++q) {
        __builtin_amdgcn_global_load_lds(
            (const __attribute__((address_space(1))) void*)(gsrc[q]),
            (__attribute__((address_space(3))) void*)(smem + loff[q]), 16, 0, 0);
        gsrc[q] += 32;
    }
    __syncthreads();

    const int NT = K >> 5;
    int cur = 0;
    for (int t = 0; t < NT; ++t) {
        if (t + 1 < NT) {
            #pragma unroll
            for (int q = 0; q < NQ; ++q) {
                __builtin_amdgcn_global_load_lds(
                    (const __attribute__((address_space(1))) void*)(gsrc[q]),
                    (__attribute__((address_space(3))) void*)(smem + loff[q] + (cur ^ BUF)),
                    16, 0, 0);
                gsrc[q] += 32;
            }
        }
        const char* sb = smem + cur;
        bf16x8 a[4], b[4];
        #pragma unroll
        for (int i = 0; i < 4; ++i) {
            int offA = (wr * 64 + i * 16 + r) * 64 + sw;
            int offB = (wc * 64 + i * 16 + r) * 64 + sw;
            a[i] = *(const bf16x8*)(sb + offA);
            b[i] = *(const bf16x8*)(sb + 8192 + offB);
        }
        __builtin_amdgcn_s_setprio(1);
        #pragma unroll
        for (int i = 0; i < 4; ++i)
            #pragma unroll
            for (int j = 0; j < 4; ++j)
                acc[i][j] = __builtin_amdgcn_mfma_f32_16x16x32_bf16(a[i], b[j], acc[i][j], 0, 0, 0);
        __builtin_amdgcn_s_setprio(0);
        __syncthreads();
        cur ^= BUF;
    }

    #pragma unroll
    for (int j = 0; j < 4; ++j) {
        int col = n0 + wc * 64 + j * 16 + r;
        float bv = bias[col];
        #pragma unroll
        for (int i = 0; i < 4; ++i) {
            int rowb = m0 + wr * 64 + i * 16 + g * 4;
            #pragma unroll
            for (int t = 0; t < 4; ++t)
                C[(size_t)(rowb + t) * Nc + col] = f2bf_rn(acc[i][j][t] + bv);
        }
    }
}

// -------- XCD swizzle for edge kernels: graph g -> XCD g%8 --------

__device__ __forceinline__ int edge_blk_swz(int blk, int swz) {
    if (swz) {
        int x = blk & 7, i = blk >> 3;
        blk = (i >> 7) * 1024 + x * 128 + (i & 127);
    }
    return blk;
}

// ---------------- Layer 1 edge kernel: wave per node, 8 ch/lane ----------------

__global__ __launch_bounds__(256) void gat_edge1(
        const unsigned short* __restrict__ xlr,
        const float* __restrict__ att, const float* __restrict__ bias,
        const int* __restrict__ roff, const int* __restrict__ csrc,
        unsigned short* __restrict__ Hh, int chunkN, int n0, int swz) {
    int blk = edge_blk_swz(blockIdx.x, swz);
    int node = blk * 4 + (threadIdx.x >> 6);
    if (node >= chunkN) return;
    int lane = threadIdx.x & 63;
    int bc = lane * 8;                 // head = lane/16
    float xrv[8], att6[8], att4[8];
    {
        uint4 t0 = *(const uint4*)&xlr[(size_t)node * 1024 + 512 + bc];
        const unsigned* u = (const unsigned*)&t0;
        #pragma unroll
        for (int j = 0; j < 4; ++j) {
            xrv[2*j]   = __uint_as_float(u[j] << 16);
            xrv[2*j+1] = __uint_as_float(u[j] & 0xFFFF0000u);
        }
        float4 a0 = *(const float4*)&att[bc];
        float4 a1 = *(const float4*)&att[bc + 4];
        float av[8] = {a0.x, a0.y, a0.z, a0.w, a1.x, a1.y, a1.z, a1.w};
        #pragma unroll
        for (int k = 0; k < 8; ++k) { att6[k] = 0.6f * av[k]; att4[k] = 0.4f * av[k]; }
    }
    float acc[8];
    float m = 0.0f, d = 0.0f;
    int e0 = roff[n0 + node], e1 = roff[n0 + node + 1];
    uint4 cv;
    {
        int s = csrc[e0] - n0;
        cv = *(const uint4*)&xlr[(size_t)s * 1024 + bc];
    }
    for (int e = e0; e < e1; ++e) {
        float xv[8];
        {
            const unsigned* u = (const unsigned*)&cv;
            #pragma unroll
            for (int j = 0; j < 4; ++j) {
                xv[2*j]   = __uint_as_float(u[j] << 16);
                xv[2*j+1] = __uint_as_float(u[j] & 0xFFFF0000u);
            }
        }
        if (e + 1 < e1) {              // prefetch next edge
            int s2 = csrc[e + 1] - n0;
            cv = *(const uint4*)&xlr[(size_t)s2 * 1024 + bc];
        }
        float p = 0.0f;
        #pragma unroll
        for (int k = 0; k < 8; ++k) {
            float t = xv[k] + xrv[k];
            p = fmaf(att6[k], t, p);
            p = fmaf(att4[k], fabsf(t), p);    // leaky = 0.6t + 0.4|t|
        }
        p += __shfl_xor(p, 1); p += __shfl_xor(p, 2);
        p += __shfl_xor(p, 4); p += __shfl_xor(p, 8);
        if (e == e0) {
            m = p; d = 1.0f;
            #pragma unroll
            for (int k = 0; k < 8; ++k) acc[k] = xv[k];
        } else if (p > m + 8.0f) {
            float sc = __expf(m - p);
            d = fmaf(d, sc, 1.0f);
            #pragma unroll
            for (int k = 0; k < 8; ++k) acc[k] = fmaf(acc[k], sc, xv[k]);
            m = p;
        } else {
            float w = __expf(p - m);
            d += w;
            #pragma unroll
            for (int k = 0; k < 8; ++k) acc[k] = fmaf(w, xv[k], acc[k]);
        }
    }
    float inv = 1.0f / d;
    ushort8 hv;
    #pragma unroll
    for (int k = 0; k < 8; ++k)
        ((unsigned short*)&hv)[k] = f2bf_rn(fmaf(acc[k], inv, bias[bc + k]));
    *(ushort8*)&Hh[(size_t)node * 512 + bc] = hv;
}

// ------- Layer 2 edge kernel: fused head-mean + feature-mean, 4 ch/lane -------

__global__ __launch_bounds__(256) void gat_edge2(
        const unsigned short* __restrict__ xlr,
        const float* __restrict__ att, const float* __restrict__ bias,
        const int* __restrict__ roff, const int* __restrict__ csrc,
        float* __restrict__ out, int chunkN, int n0, int swz) {
    int blk = edge_blk_swz(blockIdx.x, swz);
    int node = blk * 4 + (threadIdx.x >> 6);
    if (node >= chunkN) return;
    int lane = threadIdx.x & 63;
    int bc = lane * 4;                 // within [0,256); head = lane/16
    float xrv[4], att6[4], att4[4];
    {
        uint2 t0 = *(const uint2*)&xlr[(size_t)node * 512 + 256 + bc];
        const unsigned* u = (const unsigned*)&t0;
        #pragma unroll
        for (int j = 0; j < 2; ++j) {
            xrv[2*j]   = __uint_as_float(u[j] << 16);
            xrv[2*j+1] = __uint_as_float(u[j] & 0xFFFF0000u);
        }
        float4 a0 = *(const float4*)&att[bc];
        float av[4] = {a0.x, a0.y, a0.z, a0.w};
        #pragma unroll
        for (int k = 0; k < 4; ++k) { att6[k] = 0.6f * av[k]; att4[k] = 0.4f * av[k]; }
    }
    float acc[4];
    float m = 0.0f, d = 0.0f;
    int e0 = roff[n0 + node], e1 = roff[n0 + node + 1];
    uint2 cv;
    {
        int s = csrc[e0] - n0;
        cv = *(const uint2*)&xlr[(size_t)s * 512 + bc];
    }
    for (int e = e0; e < e1; ++e) {
        float xv[4];
        {
            const unsigned* u = (const unsigned*)&cv;
            #pragma unroll
            for (int j = 0; j < 2; ++j) {
                xv[2*j]   = __uint_as_float(u[j] << 16);
                xv[2*j+1] = __uint_as_float(u[j] & 0xFFFF0000u);
            }
        }
        if (e + 1 < e1) {
            int s2 = csrc[e + 1] - n0;
            cv = *(const uint2*)&xlr[(size_t)s2 * 512 + bc];
        }
        float p = 0.0f;
        #pragma unroll
        for (int k = 0; k < 4; ++k) {
            float t = xv[k] + xrv[k];
            p = fmaf(att6[k], t, p);
            p = fmaf(att4[k], fabsf(t), p);
        }
        p += __shfl_xor(p, 1); p += __shfl_xor(p, 2);
        p += __shfl_xor(p, 4); p += __shfl_xor(p, 8);
        if (e == e0) {
            m = p; d = 1.0f;
            #pragma unroll
            for (int k = 0; k < 4; ++k) acc[k] = xv[k];
        } else if (p > m + 8.0f) {
            float sc = __expf(m - p);
            d = fmaf(d, sc, 1.0f);
            #pragma unroll
            for (int k = 0; k < 4; ++k) acc[k] = fmaf(acc[k], sc, xv[k]);
            m = p;
        } else {
            float w = __expf(p - m);
            d += w;
            #pragma unroll
            for (int k = 0; k < 4; ++k) acc[k] = fmaf(w, xv[k], acc[k]);
        }
    }
    float inv = 1.0f / d;
    float v[4];
    #pragma unroll
    for (int k = 0; k < 4; ++k) v[k] = acc[k] * inv;
    #pragma unroll
    for (int k = 0; k < 4; ++k) {
        v[k] += __shfl_xor(v[k], 16);
        v[k] += __shfl_xor(v[k], 32);
    }
    int cb = (lane & 15) * 4;
    float s = 0.25f * (v[0] + v[1] + v[2] + v[3])
            + bias[cb] + bias[cb + 1] + bias[cb + 2] + bias[cb + 3];
    s += __shfl_xor(s, 1); s += __shfl_xor(s, 2);
    s += __shfl_xor(s, 4); s += __shfl_xor(s, 8);
    if (lane == 0) out[node] = s * (1.0f / 64.0f);
}

// ---------------- launch ----------------

extern "C" void kernel_launch(void* const* d_in, const int* in_sizes, int n_in,
                              void* d_out, int out_size, void* d_ws, size_t ws_size,
                              hipStream_t stream) {
    const float* x    = (const float*)d_in[0];
    const int*   ei   = (const int*)d_in[1];
    const float* Wl1  = (const float*)d_in[3];
    const float* bl1  = (const float*)d_in[4];
    const float* Wr1  = (const float*)d_in[5];
    const float* br1  = (const float*)d_in[6];
    const float* att1 = (const float*)d_in[7];
    const float* bias1= (const float*)d_in[8];
    const float* Wl2  = (const float*)d_in[9];
    const float* bl2  = (const float*)d_in[10];
    const float* Wr2  = (const float*)d_in[11];
    const float* br2  = (const float*)d_in[12];
    const float* att2 = (const float*)d_in[13];
    const float* bias2= (const float*)d_in[14];
    float* out = (float*)d_out;

    const int F = 512;
    const int N = in_sizes[0] / F;        // 32768
    const int E = in_sizes[1] / 2;        // 262144
    const int NG = 64;
    const int NPG = N / NG;               // 512
    const int EPG_NL = E / NG;            // 4096 non-loop edges per graph

    char* w = (char*)d_ws;
    int* roff = (int*)(w);                                   // N+1
    int* csrc = (int*)(w + 0x80000);                         // E+N
    unsigned short* wc1 = (unsigned short*)(w + 0x200000);   // [1024][512] bf16
    unsigned short* wc2 = (unsigned short*)(w + 0x400000);   // [512][512] bf16
    float* bcat1 = (float*)(w + 0x500000);
    float* bcat2 = (float*)(w + 0x501000);
    const size_t HDR = 6ull << 20;

    int chunkG = NG;
    while (chunkG > 1) {
        size_t need = HDR + 3ull * (size_t)chunkG * NPG * 512 * 4;
        if (need <= ws_size) break;
        chunkG >>= 1;
    }
    const int chunkN = chunkG * NPG;
    const size_t BSZ = (size_t)chunkN * 512 * 4;
    char* R1 = w + HDR;
    char* R2 = w + HDR + BSZ;
    const int swz = (chunkG % 8 == 0) ? 1 : 0;

    csr_build<<<NG, 512, 0, stream>>>(ei, E, NPG, EPG_NL, roff, csrc);
    tcast4_kernel<<<dim3(16, 16, 4), 256, 0, stream>>>(Wl1, Wr1, Wl2, Wr2, wc1, wc2);
    bconcat_kernel<<<3, 512, 0, stream>>>(bl1, br1, bl2, br2, bcat1, bcat2);

    for (int g0 = 0; g0 < NG; g0 += chunkG) {
        int n0 = g0 * NPG;
        const float* xc = x + (size_t)n0 * 512;
        unsigned short* xlr1 = (unsigned short*)R2;  // bf16 [chunkN][1024]
        unsigned short* Hh   = (unsigned short*)R1;  // bf16 [chunkN][512]
        unsigned short* xlr2 = (unsigned short*)R2;  // bf16 [chunkN][512]

        gemm128f<<<dim3(1024/128, chunkN/128), 256, 0, stream>>>(
            xc, wc1, bcat1, xlr1, chunkN, 512, 1024);
        gat_edge1<<<(chunkN * 64) / 256, 256, 0, stream>>>(
            xlr1, att1, bias1, roff, csrc, Hh, chunkN, n0, swz);

        gemm128b<<<dim3(512/128, chunkN/128), 256, 0, stream>>>(
            Hh, wc2, bcat2, xlr2, chunkN, 512, 512);
        gat_edge2<<<(chunkN * 64) / 256, 256, 0, stream>>>(
            xlr2, att2, bias2, roff, csrc, out + n0, chunkN, n0, swz);
    }
}

// Round 20
// 170.229 us; speedup vs baseline: 1.5118x; 1.0201x over previous
//
#include <hip/hip_runtime.h>
#include <hip/hip_bf16.h>

// GATv2 2-layer GNN. Round 20: fix round-19's A-staging coalescing in the L1
// GEMM — load q covers contiguous 4KB fp32 segment (wave-linear dwordx4),
// pack 4 fp32 -> 4 bf16, ds_write_b64 to the swizzled slot. Loads issued
// before MFMA, writes after (T14 split). Everything else = round 19.
// N=32768 (64 graphs x 512), F=512, E=262144 (+N self loops), H=4, C1=128, C2=64.

typedef __bf16 bf16_t;
typedef bf16_t bf16x8 __attribute__((ext_vector_type(8)));
typedef float f32x4 __attribute__((ext_vector_type(4)));
typedef unsigned short ushort8 __attribute__((ext_vector_type(8)));

__device__ __forceinline__ unsigned short f2bf_rn(float f) {
    unsigned u = __float_as_uint(f);
    unsigned r = (u + 0x7FFFu + ((u >> 16) & 1u)) >> 16;
    return (unsigned short)r;
}

// ------------- CSR build: one block (512 thr) per graph, all in LDS ---------

__global__ __launch_bounds__(512) void csr_build(
        const int* __restrict__ ei, int E, int NPG, int EPG_NL,
        int* __restrict__ roff, int* __restrict__ csrc) {
    __shared__ int deg[512], buf[512], soff[512], cnt[512];
    int g = blockIdx.x, tid = threadIdx.x;
    int nb = g * NPG;
    int eb = g * EPG_NL;
    const int EPG = EPG_NL + NPG;
    deg[tid] = 1;                      // self loop
    __syncthreads();
    for (int i = tid; i < EPG_NL; i += 512)
        atomicAdd(&deg[ei[E + eb + i] - nb], 1);
    __syncthreads();
    buf[tid] = deg[tid];
    __syncthreads();
    #pragma unroll
    for (int ofs = 1; ofs < 512; ofs <<= 1) {
        int t = (tid >= ofs) ? buf[tid - ofs] : 0;
        __syncthreads();
        buf[tid] += t;
        __syncthreads();
    }
    int oe = buf[tid] - deg[tid];
    soff[tid] = oe;
    roff[nb + tid] = g * EPG + oe;
    if (tid == 511) roff[nb + 512] = g * EPG + buf[511];
    cnt[tid] = 1;
    csrc[g * EPG + oe] = nb + tid;
    __syncthreads();
    for (int i = tid; i < EPG_NL; i += 512) {
        int dl = ei[E + eb + i] - nb;
        int s  = ei[eb + i];
        int pos = atomicAdd(&cnt[dl], 1);
        csrc[g * EPG + soff[dl] + pos] = s;
    }
}

// All 4 weights: W [K][Nc] fp32 -> Wt [Nc][K] bf16 (transpose+cast), one launch.
__global__ __launch_bounds__(256) void tcast4_kernel(
        const float* __restrict__ Wl1, const float* __restrict__ Wr1,
        const float* __restrict__ Wl2, const float* __restrict__ Wr2,
        unsigned short* __restrict__ wc1, unsigned short* __restrict__ wc2) {
    int z = blockIdx.z;
    int Nc = (z < 2) ? 512 : 256;
    if (blockIdx.x * 32 >= Nc) return;
    const float* W = (z == 0) ? Wl1 : (z == 1) ? Wr1 : (z == 2) ? Wl2 : Wr2;
    unsigned short* th = (z == 0) ? wc1 : (z == 1) ? wc1 + 512 * 512
                       : (z == 2) ? wc2 : wc2 + 256 * 512;
    const int K = 512;
    __shared__ float t[32][33];
    int bx = blockIdx.x, by = blockIdx.y;
    int lx = threadIdx.x & 31, ly = threadIdx.x >> 5;
    #pragma unroll
    for (int r = ly; r < 32; r += 8)
        t[r][lx] = W[(size_t)(by * 32 + r) * Nc + bx * 32 + lx];
    __syncthreads();
    #pragma unroll
    for (int r = ly; r < 32; r += 8)
        th[(size_t)(bx * 32 + r) * K + by * 32 + lx] = f2bf_rn(t[lx][r]);
}

// bias concat: bcat1 = [bl1|br1] (1024), bcat2 = [bl2|br2] (512)
__global__ __launch_bounds__(512) void bconcat_kernel(
        const float* __restrict__ bl1, const float* __restrict__ br1,
        const float* __restrict__ bl2, const float* __restrict__ br2,
        float* __restrict__ bcat1, float* __restrict__ bcat2) {
    int i = blockIdx.x * 512 + threadIdx.x;
    if (i < 512)        bcat1[i] = bl1[i];
    else if (i < 1024)  bcat1[i] = br1[i - 512];
    else if (i < 1280)  bcat2[i - 1024] = bl2[i - 1024];
    else if (i < 1536)  bcat2[i - 1024] = br2[i - 1280];
}

// ---- L1 GEMM: 128x128, 4 waves, A = fp32 coalesced reg-staged -> bf16 LDS ----
// C(bf16) = bf16(A_fp32)@B^T + bias. B bf16 [Nc][K] via global_load_lds.
// A: load q = contiguous 4KB fp32 segment (o = q*4096 + tid*16), pack -> 8B
// bf16, ds_write_b64 to row*64 + (slot^key)*16 + (bcol&8). key=(row>>1)&3.

__global__ __launch_bounds__(256) void gemm128f(
        const float* __restrict__ A,
        const unsigned short* __restrict__ B,
        const float* __restrict__ bias, unsigned short* __restrict__ C,
        int M, int K, int Nc) {
    constexpr int BUF = 16384;                  // A(8KB) | B(8KB)
    __shared__ __align__(16) char smem[2 * BUF];

    int tid  = threadIdx.x;
    int wave = tid >> 6, lane = tid & 63;
    int wr = wave >> 1, wc = wave & 1;

    int bx = blockIdx.x, by = blockIdx.y;
    if ((gridDim.y & 7) == 0) {                 // XCD swizzle
        int d = blockIdx.y * gridDim.x + blockIdx.x;
        int x = d & 7, i = d >> 3;
        by = (i / gridDim.x) * 8 + x;
        bx = i % gridDim.x;
    }
    int m0 = by * 128, n0 = bx * 128;

    // B DMA staging (2 loads cover the 8KB B tile)
    const unsigned short* gsrcB[2];
    int loffB[2];
    #pragma unroll
    for (int q = 0; q < 2; ++q) {
        int o    = q * 4096 + tid * 16;
        int row  = o >> 6;
        int slot = (o >> 4) & 3;
        int sl   = slot ^ ((row >> 1) & 3);
        gsrcB[q] = B + (size_t)(n0 + row) * K + sl * 8;
        loffB[q] = 8192 + q * 4096 + wave * 1024;
    }
    // A coalesced reg staging: load q covers fp32 bytes [q*4096+tid*16, +16)
    const float* asrcA[4];
    int awoff[4];
    #pragma unroll
    for (int q = 0; q < 4; ++q) {
        int o    = q * 4096 + tid * 16;         // fp32 tile byte offset (16KB)
        int row  = o >> 7;                      // 128B per fp32 row
        int fb   = o & 127;                     // in-row fp32 byte
        int bcol = fb >> 1;                     // in-row bf16 byte (0..63)
        int sl   = (bcol >> 4) ^ ((row >> 1) & 3);
        asrcA[q] = A + (size_t)(m0 + row) * K + (fb >> 2);
        awoff[q] = row * 64 + sl * 16 + (bcol & 8);
    }

    f32x4 acc[4][4];
    #pragma unroll
    for (int i = 0; i < 4; ++i)
        #pragma unroll
        for (int j = 0; j < 4; ++j) acc[i][j] = (f32x4){0.f, 0.f, 0.f, 0.f};

    int r = lane & 15, g = lane >> 4;
    int sw = (g ^ ((r >> 1) & 3)) * 16;

    // prologue: stage tile 0
    float4 areg[4];
    #pragma unroll
    for (int q = 0; q < 4; ++q) { areg[q] = *(const float4*)asrcA[q]; asrcA[q] += 32; }
    #pragma unroll
    for (int q = 0; q < 2; ++q) {
        __builtin_amdgcn_global_load_lds(
            (const __attribute__((address_space(1))) void*)(gsrcB[q]),
            (__attribute__((address_space(3))) void*)(smem + loffB[q]), 16, 0, 0);
        gsrcB[q] += 32;
    }
    #pragma unroll
    for (int q = 0; q < 4; ++q) {
        ushort4 p;
        p.x = f2bf_rn(areg[q].x); p.y = f2bf_rn(areg[q].y);
        p.z = f2bf_rn(areg[q].z); p.w = f2bf_rn(areg[q].w);
        *(ushort4*)(smem + awoff[q]) = p;
    }
    __syncthreads();

    const int NT = K >> 5;
    int cur = 0;
    for (int t = 0; t < NT; ++t) {
        bool pre = (t + 1 < NT);
        if (pre) {                              // issue next tile's loads EARLY
            #pragma unroll
            for (int q = 0; q < 4; ++q) { areg[q] = *(const float4*)asrcA[q]; asrcA[q] += 32; }
            #pragma unroll
            for (int q = 0; q < 2; ++q) {
                __builtin_amdgcn_global_load_lds(
                    (const __attribute__((address_space(1))) void*)(gsrcB[q]),
                    (__attribute__((address_space(3))) void*)(smem + loffB[q] + (cur ^ BUF)),
                    16, 0, 0);
                gsrcB[q] += 32;
            }
        }
        const char* sb = smem + cur;
        bf16x8 a[4], b[4];
        #pragma unroll
        for (int i = 0; i < 4; ++i) {
            int offA = (wr * 64 + i * 16 + r) * 64 + sw;
            int offB = (wc * 64 + i * 16 + r) * 64 + sw;
            a[i] = *(const bf16x8*)(sb + offA);
            b[i] = *(const bf16x8*)(sb + 8192 + offB);
        }
        __builtin_amdgcn_s_setprio(1);
        #pragma unroll
        for (int i = 0; i < 4; ++i)
            #pragma unroll
            for (int j = 0; j < 4; ++j)
                acc[i][j] = __builtin_amdgcn_mfma_f32_16x16x32_bf16(a[i], b[j], acc[i][j], 0, 0, 0);
        __builtin_amdgcn_s_setprio(0);
        if (pre) {                              // pack + write A(t+1) late
            #pragma unroll
            for (int q = 0; q < 4; ++q) {
                ushort4 p;
                p.x = f2bf_rn(areg[q].x); p.y = f2bf_rn(areg[q].y);
                p.z = f2bf_rn(areg[q].z); p.w = f2bf_rn(areg[q].w);
                *(ushort4*)(smem + (cur ^ BUF) + awoff[q]) = p;
            }
        }
        __syncthreads();
        cur ^= BUF;
    }

    #pragma unroll
    for (int j = 0; j < 4; ++j) {
        int col = n0 + wc * 64 + j * 16 + r;
        float bv = bias[col];
        #pragma unroll
        for (int i = 0; i < 4; ++i) {
            int rowb = m0 + wr * 64 + i * 16 + g * 4;
            #pragma unroll
            for (int t = 0; t < 4; ++t)
                C[(size_t)(rowb + t) * Nc + col] = f2bf_rn(acc[i][j][t] + bv);
        }
    }
}

// ---- L2 GEMM: 128x128, 4 waves, pure bf16 A/B via DMA ----

__global__ __launch_bounds__(256) void gemm128b(
        const unsigned short* __restrict__ A,
        const unsigned short* __restrict__ B,
        const float* __restrict__ bias, unsigned short* __restrict__ C,
        int M, int K, int Nc) {
    constexpr int NQ  = 4;
    constexpr int BUF = 16384;
    __shared__ __align__(16) char smem[2 * BUF];

    int tid  = threadIdx.x;
    int wave = tid >> 6, lane = tid & 63;
    int wr = wave >> 1, wc = wave & 1;

    int bx = blockIdx.x, by = blockIdx.y;
    if ((gridDim.y & 7) == 0) {
        int d = blockIdx.y * gridDim.x + blockIdx.x;
        int x = d & 7, i = d >> 3;
        by = (i / gridDim.x) * 8 + x;
        bx = i % gridDim.x;
    }
    int m0 = by * 128, n0 = bx * 128;

    const unsigned short* gsrc[NQ];
    int loff[NQ];
    #pragma unroll
    for (int q = 0; q < NQ; ++q) {
        int o    = q * 4096 + tid * 16;
        int tile = o >> 13;
        int ot   = o & 8191;
        int row  = ot >> 6;
        int slot = (ot >> 4) & 3;
        int sl   = slot ^ ((row >> 1) & 3);
        const unsigned short* base =
            (tile == 0) ? (A + (size_t)(m0 + row) * K)
                        : (B + (size_t)(n0 + row) * K);
        gsrc[q] = base + sl * 8;
        loff[q] = q * 4096 + wave * 1024;
    }

    f32x4 acc[4][4];
    #pragma unroll
    for (int i = 0; i < 4; ++i)
        #pragma unroll
        for (int j = 0; j < 4; ++j) acc[i][j] = (f32x4){0.f, 0.f, 0.f, 0.f};

    int r = lane & 15, g = lane >> 4;
    int sw = (g ^ ((r >> 1) & 3)) * 16;

    #pragma unroll
    for (int q = 0; q < NQ; ++q) {
        __builtin_amdgcn_global_load_lds(
            (const __attribute__((address_space(1))) void*)(gsrc[q]),
            (__attribute__((address_space(3))) void*)(smem + loff[q]), 16, 0, 0);
        gsrc[q] += 32;
    }
    __syncthreads();

    const int NT = K >> 5;
    int cur = 0;
    for (int t = 0; t < NT; ++t) {
        if (t + 1 < NT) {
            #pragma unroll
            for (int q = 0; q < NQ; ++q) {
                __builtin_amdgcn_global_load_lds(
                    (const __attribute__((address_space(1))) void*)(gsrc[q]),
                    (__attribute__((address_space(3))) void*)(smem + loff[q] + (cur ^ BUF)),
                    16, 0, 0);
                gsrc[q] += 32;
            }
        }
        const char* sb = smem + cur;
        bf16x8 a[4], b[4];
        #pragma unroll
        for (int i = 0; i < 4; ++i) {
            int offA = (wr * 64 + i * 16 + r) * 64 + sw;
            int offB = (wc * 64 + i * 16 + r) * 64 + sw;
            a[i] = *(const bf16x8*)(sb + offA);
            b[i] = *(const bf16x8*)(sb + 8192 + offB);
        }
        __builtin_amdgcn_s_setprio(1);
        #pragma unroll
        for (int i = 0; i < 4; ++i)
            #pragma unroll
            for (int j = 0; j < 4; ++j)
                acc[i][j] = __builtin_amdgcn_mfma_f32_16x16x32_bf16(a[i], b[j], acc[i][j], 0, 0, 0);
        __builtin_amdgcn_s_setprio(0);
        __syncthreads();
        cur ^= BUF;
    }

    #pragma unroll
    for (int j = 0; j < 4; ++j) {
        int col = n0 + wc * 64 + j * 16 + r;
        float bv = bias[col];
        #pragma unroll
        for (int i = 0; i < 4; ++i) {
            int rowb = m0 + wr * 64 + i * 16 + g * 4;
            #pragma unroll
            for (int t = 0; t < 4; ++t)
                C[(size_t)(rowb + t) * Nc + col] = f2bf_rn(acc[i][j][t] + bv);
        }
    }
}

// -------- XCD swizzle for edge kernels: graph g -> XCD g%8 --------

__device__ __forceinline__ int edge_blk_swz(int blk, int swz) {
    if (swz) {
        int x = blk & 7, i = blk >> 3;
        blk = (i >> 7) * 1024 + x * 128 + (i & 127);
    }
    return blk;
}

// ---------------- Layer 1 edge kernel: wave per node, 8 ch/lane ----------------

__global__ __launch_bounds__(256) void gat_edge1(
        const unsigned short* __restrict__ xlr,
        const float* __restrict__ att, const float* __restrict__ bias,
        const int* __restrict__ roff, const int* __restrict__ csrc,
        unsigned short* __restrict__ Hh, int chunkN, int n0, int swz) {
    int blk = edge_blk_swz(blockIdx.x, swz);
    int node = blk * 4 + (threadIdx.x >> 6);
    if (node >= chunkN) return;
    int lane = threadIdx.x & 63;
    int bc = lane * 8;                 // head = lane/16
    float xrv[8], att6[8], att4[8];
    {
        uint4 t0 = *(const uint4*)&xlr[(size_t)node * 1024 + 512 + bc];
        const unsigned* u = (const unsigned*)&t0;
        #pragma unroll
        for (int j = 0; j < 4; ++j) {
            xrv[2*j]   = __uint_as_float(u[j] << 16);
            xrv[2*j+1] = __uint_as_float(u[j] & 0xFFFF0000u);
        }
        float4 a0 = *(const float4*)&att[bc];
        float4 a1 = *(const float4*)&att[bc + 4];
        float av[8] = {a0.x, a0.y, a0.z, a0.w, a1.x, a1.y, a1.z, a1.w};
        #pragma unroll
        for (int k = 0; k < 8; ++k) { att6[k] = 0.6f * av[k]; att4[k] = 0.4f * av[k]; }
    }
    float acc[8];
    float m = 0.0f, d = 0.0f;
    int e0 = roff[n0 + node], e1 = roff[n0 + node + 1];
    uint4 cv;
    {
        int s = csrc[e0] - n0;
        cv = *(const uint4*)&xlr[(size_t)s * 1024 + bc];
    }
    for (int e = e0; e < e1; ++e) {
        float xv[8];
        {
            const unsigned* u = (const unsigned*)&cv;
            #pragma unroll
            for (int j = 0; j < 4; ++j) {
                xv[2*j]   = __uint_as_float(u[j] << 16);
                xv[2*j+1] = __uint_as_float(u[j] & 0xFFFF0000u);
            }
        }
        if (e + 1 < e1) {              // prefetch next edge
            int s2 = csrc[e + 1] - n0;
            cv = *(const uint4*)&xlr[(size_t)s2 * 1024 + bc];
        }
        float p = 0.0f;
        #pragma unroll
        for (int k = 0; k < 8; ++k) {
            float t = xv[k] + xrv[k];
            p = fmaf(att6[k], t, p);
            p = fmaf(att4[k], fabsf(t), p);    // leaky = 0.6t + 0.4|t|
        }
        p += __shfl_xor(p, 1); p += __shfl_xor(p, 2);
        p += __shfl_xor(p, 4); p += __shfl_xor(p, 8);
        if (e == e0) {
            m = p; d = 1.0f;
            #pragma unroll
            for (int k = 0; k < 8; ++k) acc[k] = xv[k];
        } else if (p > m + 8.0f) {
            float sc = __expf(m - p);
            d = fmaf(d, sc, 1.0f);
            #pragma unroll
            for (int k = 0; k < 8; ++k) acc[k] = fmaf(acc[k], sc, xv[k]);
            m = p;
        } else {
            float w = __expf(p - m);
            d += w;
            #pragma unroll
            for (int k = 0; k < 8; ++k) acc[k] = fmaf(w, xv[k], acc[k]);
        }
    }
    float inv = 1.0f / d;
    ushort8 hv;
    #pragma unroll
    for (int k = 0; k < 8; ++k)
        ((unsigned short*)&hv)[k] = f2bf_rn(fmaf(acc[k], inv, bias[bc + k]));
    *(ushort8*)&Hh[(size_t)node * 512 + bc] = hv;
}

// ------- Layer 2 edge kernel: fused head-mean + feature-mean, 4 ch/lane -------

__global__ __launch_bounds__(256) void gat_edge2(
        const unsigned short* __restrict__ xlr,
        const float* __restrict__ att, const float* __restrict__ bias,
        const int* __restrict__ roff, const int* __restrict__ csrc,
        float* __restrict__ out, int chunkN, int n0, int swz) {
    int blk = edge_blk_swz(blockIdx.x, swz);
    int node = blk * 4 + (threadIdx.x >> 6);
    if (node >= chunkN) return;
    int lane = threadIdx.x & 63;
    int bc = lane * 4;                 // within [0,256); head = lane/16
    float xrv[4], att6[4], att4[4];
    {
        uint2 t0 = *(const uint2*)&xlr[(size_t)node * 512 + 256 + bc];
        const unsigned* u = (const unsigned*)&t0;
        #pragma unroll
        for (int j = 0; j < 2; ++j) {
            xrv[2*j]   = __uint_as_float(u[j] << 16);
            xrv[2*j+1] = __uint_as_float(u[j] & 0xFFFF0000u);
        }
        float4 a0 = *(const float4*)&att[bc];
        float av[4] = {a0.x, a0.y, a0.z, a0.w};
        #pragma unroll
        for (int k = 0; k < 4; ++k) { att6[k] = 0.6f * av[k]; att4[k] = 0.4f * av[k]; }
    }
    float acc[4];
    float m = 0.0f, d = 0.0f;
    int e0 = roff[n0 + node], e1 = roff[n0 + node + 1];
    uint2 cv;
    {
        int s = csrc[e0] - n0;
        cv = *(const uint2*)&xlr[(size_t)s * 512 + bc];
    }
    for (int e = e0; e < e1; ++e) {
        float xv[4];
        {
            const unsigned* u = (const unsigned*)&cv;
            #pragma unroll
            for (int j = 0; j < 2; ++j) {
                xv[2*j]   = __uint_as_float(u[j] << 16);
                xv[2*j+1] = __uint_as_float(u[j] & 0xFFFF0000u);
            }
        }
        if (e + 1 < e1) {
            int s2 = csrc[e + 1] - n0;
            cv = *(const uint2*)&xlr[(size_t)s2 * 512 + bc];
        }
        float p = 0.0f;
        #pragma unroll
        for (int k = 0; k < 4; ++k) {
            float t = xv[k] + xrv[k];
            p = fmaf(att6[k], t, p);
            p = fmaf(att4[k], fabsf(t), p);
        }
        p += __shfl_xor(p, 1); p += __shfl_xor(p, 2);
        p += __shfl_xor(p, 4); p += __shfl_xor(p, 8);
        if (e == e0) {
            m = p; d = 1.0f;
            #pragma unroll
            for (int k = 0; k < 4; ++k) acc[k] = xv[k];
        } else if (p > m + 8.0f) {
            float sc = __expf(m - p);
            d = fmaf(d, sc, 1.0f);
            #pragma unroll
            for (int k = 0; k < 4; ++k) acc[k] = fmaf(acc[k], sc, xv[k]);
            m = p;
        } else {
            float w = __expf(p - m);
            d += w;
            #pragma unroll
            for (int k = 0; k < 4; ++k) acc[k] = fmaf(w, xv[k], acc[k]);
        }
    }
    float inv = 1.0f / d;
    float v[4];
    #pragma unroll
    for (int k = 0; k < 4; ++k) v[k] = acc[k] * inv;
    #pragma unroll
    for (int k = 0; k < 4; ++k) {
        v[k] += __shfl_xor(v[k], 16);
        v[k] += __shfl_xor(v[k], 32);
    }
    int cb = (lane & 15) * 4;
    float s = 0.25f * (v[0] + v[1] + v[2] + v[3])
            + bias[cb] + bias[cb + 1] + bias[cb + 2] + bias[cb + 3];
    s += __shfl_xor(s, 1); s += __shfl_xor(s, 2);
    s += __shfl_xor(s, 4); s += __shfl_xor(s, 8);
    if (lane == 0) out[node] = s * (1.0f / 64.0f);
}

// ---------------- launch ----------------

extern "C" void kernel_launch(void* const* d_in, const int* in_sizes, int n_in,
                              void* d_out, int out_size, void* d_ws, size_t ws_size,
                              hipStream_t stream) {
    const float* x    = (const float*)d_in[0];
    const int*   ei   = (const int*)d_in[1];
    const float* Wl1  = (const float*)d_in[3];
    const float* bl1  = (const float*)d_in[4];
    const float* Wr1  = (const float*)d_in[5];
    const float* br1  = (const float*)d_in[6];
    const float* att1 = (const float*)d_in[7];
    const float* bias1= (const float*)d_in[8];
    const float* Wl2  = (const float*)d_in[9];
    const float* bl2  = (const float*)d_in[10];
    const float* Wr2  = (const float*)d_in[11];
    const float* br2  = (const float*)d_in[12];
    const float* att2 = (const float*)d_in[13];
    const float* bias2= (const float*)d_in[14];
    float* out = (float*)d_out;

    const int F = 512;
    const int N = in_sizes[0] / F;        // 32768
    const int E = in_sizes[1] / 2;        // 262144
    const int NG = 64;
    const int NPG = N / NG;               // 512
    const int EPG_NL = E / NG;            // 4096 non-loop edges per graph

    char* w = (char*)d_ws;
    int* roff = (int*)(w);                                   // N+1
    int* csrc = (int*)(w + 0x80000);                         // E+N
    unsigned short* wc1 = (unsigned short*)(w + 0x200000);   // [1024][512] bf16
    unsigned short* wc2 = (unsigned short*)(w + 0x400000);   // [512][512] bf16
    float* bcat1 = (float*)(w + 0x500000);
    float* bcat2 = (float*)(w + 0x501000);
    const size_t HDR = 6ull << 20;

    int chunkG = NG;
    while (chunkG > 1) {
        size_t need = HDR + 3ull * (size_t)chunkG * NPG * 512 * 4;
        if (need <= ws_size) break;
        chunkG >>= 1;
    }
    const int chunkN = chunkG * NPG;
    const size_t BSZ = (size_t)chunkN * 512 * 4;
    char* R1 = w + HDR;
    char* R2 = w + HDR + BSZ;
    const int swz = (chunkG % 8 == 0) ? 1 : 0;

    csr_build<<<NG, 512, 0, stream>>>(ei, E, NPG, EPG_NL, roff, csrc);
    tcast4_kernel<<<dim3(16, 16, 4), 256, 0, stream>>>(Wl1, Wr1, Wl2, Wr2, wc1, wc2);
    bconcat_kernel<<<3, 512, 0, stream>>>(bl1, br1, bl2, br2, bcat1, bcat2);

    for (int g0 = 0; g0 < NG; g0 += chunkG) {
        int n0 = g0 * NPG;
        const float* xc = x + (size_t)n0 * 512;
        unsigned short* xlr1 = (unsigned short*)R2;  // bf16 [chunkN][1024]
        unsigned short* Hh   = (unsigned short*)R1;  // bf16 [chunkN][512]
        unsigned short* xlr2 = (unsigned short*)R2;  // bf16 [chunkN][512]

        gemm128f<<<dim3(1024/128, chunkN/128), 256, 0, stream>>>(
            xc, wc1, bcat1, xlr1, chunkN, 512, 1024);
        gat_edge1<<<(chunkN * 64) / 256, 256, 0, stream>>>(
            xlr1, att1, bias1, roff, csrc, Hh, chunkN, n0, swz);

        gemm128b<<<dim3(512/128, chunkN/128), 256, 0, stream>>>(
            Hh, wc2, bcat2, xlr2, chunkN, 512, 512);
        gat_edge2<<<(chunkN * 64) / 256, 256, 0, stream>>>(
            xlr2, att2, bias2, roff, csrc, out + n0, chunkN, n0, swz);
    }
}